// Round 1
// baseline (1156.839 us; speedup 1.0000x reference)
//
#include <hip/hip_runtime.h>

#define NN   50000
#define EE   800000
#define ETOT 850000   // EE + NN self loops
#define FIN  128
#define HC   256      // H*C
#define NH   4
#define CH   64
#define NG   64
#define NOUT 16
#define NEG_SLOPE 0.2f

// ---------------- online softmax combine (sentinel -1e30 avoids NaN) ----------
__device__ __forceinline__ void sm_combine(float& m, float& s, float om, float os) {
    float M = fmaxf(m, om);
    s = s * __expf(m - M) + os * __expf(om - M);
    m = M;
}

// ---------------- CSR build ----------------
__global__ void count_dst(const int* __restrict__ ei, int* __restrict__ cnt) {
    int i = blockIdx.x * 256 + threadIdx.x;
    if (i >= ETOT) return;
    int dst = (i < EE) ? ei[EE + i] : (i - EE);
    atomicAdd(&cnt[dst], 1);
}

__global__ __launch_bounds__(1024) void scan_kernel(const int* __restrict__ cnt,
                                                    int* __restrict__ rowptr) {
    __shared__ int lds[1024];
    __shared__ int carry_s;
    int tid = threadIdx.x;
    if (tid == 0) { carry_s = 0; rowptr[0] = 0; }
    __syncthreads();
    for (int base = 0; base < NN; base += 1024) {
        int i = base + tid;
        int v = (i < NN) ? cnt[i] : 0;
        lds[tid] = v;
        __syncthreads();
        for (int off = 1; off < 1024; off <<= 1) {
            int t = (tid >= off) ? lds[tid - off] : 0;
            __syncthreads();
            lds[tid] += t;
            __syncthreads();
        }
        int incl = lds[tid] + carry_s;
        if (i < NN) rowptr[i + 1] = incl;
        __syncthreads();
        if (tid == 1023) carry_s = incl;
        __syncthreads();
    }
}

__global__ void copy_cursor(const int* __restrict__ rowptr, int* __restrict__ cur) {
    int i = blockIdx.x * 256 + threadIdx.x;
    if (i < NN) cur[i] = rowptr[i];
}

__global__ void scatter_edges(const int* __restrict__ ei, int* __restrict__ cur,
                              int* __restrict__ csr_src) {
    int i = blockIdx.x * 256 + threadIdx.x;
    if (i >= ETOT) return;
    int src = (i < EE) ? ei[i] : (i - EE);
    int dst = (i < EE) ? ei[EE + i] : (i - EE);
    int pos = atomicAdd(&cur[dst], 1);
    csr_src[pos] = src;
}

// ---------------- f32 GEMM: C[M,256] = A[M,K] @ B[K,256] ----------------
__global__ __launch_bounds__(256) void gemm_f32(const float* __restrict__ A,
                                                const float* __restrict__ B,
                                                float* __restrict__ C,
                                                int M, int K) {
    __shared__ float As[16][128];   // transposed A tile [k][m]
    __shared__ float Bs[16][128];
    const int tid = threadIdx.x;
    const int tx = tid & 15, ty = tid >> 4;
    const int m0 = blockIdx.y * 128;
    const int n0 = blockIdx.x * 128;

    float acc[8][8];
#pragma unroll
    for (int i = 0; i < 8; ++i)
#pragma unroll
        for (int j = 0; j < 8; ++j) acc[i][j] = 0.f;

    const int lrow = tid >> 2;   // 0..63
    const int lq   = tid & 3;    // 0..3
    const int brow = tid >> 4;   // 0..15
    const int bq   = tid & 15;   // 0..15

    for (int kt = 0; kt < K; kt += 16) {
#pragma unroll
        for (int rr = 0; rr < 2; ++rr) {
            int row  = lrow + rr * 64;
            int grow = m0 + row;
            float4 v = make_float4(0.f, 0.f, 0.f, 0.f);
            if (grow < M) v = *(const float4*)&A[(size_t)grow * K + kt + lq * 4];
            As[lq * 4 + 0][row] = v.x;
            As[lq * 4 + 1][row] = v.y;
            As[lq * 4 + 2][row] = v.z;
            As[lq * 4 + 3][row] = v.w;
        }
        float4 bv0 = *(const float4*)&B[(size_t)(kt + brow) * HC + n0 + bq * 8];
        float4 bv1 = *(const float4*)&B[(size_t)(kt + brow) * HC + n0 + bq * 8 + 4];
        *(float4*)&Bs[brow][bq * 8]     = bv0;
        *(float4*)&Bs[brow][bq * 8 + 4] = bv1;
        __syncthreads();
#pragma unroll
        for (int k = 0; k < 16; ++k) {
            float4 a0 = *(const float4*)&As[k][ty * 8];
            float4 a1 = *(const float4*)&As[k][ty * 8 + 4];
            float4 b0 = *(const float4*)&Bs[k][tx * 8];
            float4 b1 = *(const float4*)&Bs[k][tx * 8 + 4];
            float av[8] = {a0.x, a0.y, a0.z, a0.w, a1.x, a1.y, a1.z, a1.w};
            float bw[8] = {b0.x, b0.y, b0.z, b0.w, b1.x, b1.y, b1.z, b1.w};
#pragma unroll
            for (int i = 0; i < 8; ++i)
#pragma unroll
                for (int j = 0; j < 8; ++j)
                    acc[i][j] = fmaf(av[i], bw[j], acc[i][j]);
        }
        __syncthreads();
    }
#pragma unroll
    for (int i = 0; i < 8; ++i) {
        int row = m0 + ty * 8 + i;
        if (row < M) {
            float4 o0 = make_float4(acc[i][0], acc[i][1], acc[i][2], acc[i][3]);
            float4 o1 = make_float4(acc[i][4], acc[i][5], acc[i][6], acc[i][7]);
            *(float4*)&C[(size_t)row * HC + n0 + tx * 8]     = o0;
            *(float4*)&C[(size_t)row * HC + n0 + tx * 8 + 4] = o1;
        }
    }
}

// ---------------- per-node attention scores ----------------
__global__ __launch_bounds__(256) void attn_scores(const float* __restrict__ h,
                                                   const float* __restrict__ a_src,
                                                   const float* __restrict__ a_dst,
                                                   float* __restrict__ es,
                                                   float* __restrict__ ed) {
    int node = blockIdx.x * 4 + (threadIdx.x >> 6);
    int lane = threadIdx.x & 63;
    if (node >= NN) return;
#pragma unroll
    for (int hh = 0; hh < NH; ++hh) {
        float v  = h[(size_t)node * HC + hh * CH + lane];
        float ps = v * a_src[hh * CH + lane];
        float pd = v * a_dst[hh * CH + lane];
#pragma unroll
        for (int off = 32; off > 0; off >>= 1) {
            ps += __shfl_xor(ps, off);
            pd += __shfl_xor(pd, off);
        }
        if (lane == 0) {
            es[node * NH + hh] = ps;
            ed[node * NH + hh] = pd;
        }
    }
}

// ---------------- GAT softmax + aggregate (one block per dst node) ----------
__global__ __launch_bounds__(256) void gat_aggregate(const float* __restrict__ hfeat,
                                                     const float* __restrict__ es,
                                                     const float* __restrict__ ed,
                                                     const int* __restrict__ rowptr,
                                                     const int* __restrict__ csr_src,
                                                     const float* __restrict__ bias,
                                                     float* __restrict__ out) {
    const int n    = blockIdx.x;
    const int tid  = threadIdx.x;
    const int lane = tid & 63;
    const int wave = tid >> 6;   // == head for this thread's channel
    const int start = rowptr[n];
    const int deg   = rowptr[n + 1] - start;

    float edn[NH];
#pragma unroll
    for (int h = 0; h < NH; ++h) edn[h] = ed[n * NH + h];

    float m[NH], s[NH];
#pragma unroll
    for (int h = 0; h < NH; ++h) { m[h] = -1e30f; s[h] = 0.f; }

    for (int j = tid; j < deg; j += 256) {
        int src = csr_src[start + j];
        float4 e4 = *(const float4*)&es[src * NH];
        float ev[NH] = {e4.x, e4.y, e4.z, e4.w};
#pragma unroll
        for (int h = 0; h < NH; ++h) {
            float e = ev[h] + edn[h];
            e = (e > 0.f) ? e : NEG_SLOPE * e;
            sm_combine(m[h], s[h], e, 1.0f);
        }
    }
    // wave butterfly reduce
#pragma unroll
    for (int h = 0; h < NH; ++h)
#pragma unroll
        for (int off = 32; off > 0; off >>= 1) {
            float om = __shfl_xor(m[h], off);
            float os = __shfl_xor(s[h], off);
            sm_combine(m[h], s[h], om, os);
        }
    __shared__ float rm[4][NH], rs[4][NH];
    __shared__ float fm[NH], fs[NH];
    if (lane == 0)
#pragma unroll
        for (int h = 0; h < NH; ++h) { rm[wave][h] = m[h]; rs[wave][h] = s[h]; }
    __syncthreads();
    if (tid < NH) {
        float M = rm[0][tid], S = rs[0][tid];
#pragma unroll
        for (int w = 1; w < 4; ++w) sm_combine(M, S, rm[w][tid], rs[w][tid]);
        fm[tid] = M; fs[tid] = S;
    }
    __syncthreads();

    const float mh    = fm[wave];
    const float inv_s = 1.0f / fs[wave];
    const float eh    = edn[wave];
    float acc = 0.f;
    for (int j = 0; j < deg; ++j) {
        int src = csr_src[start + j];
        float e = es[src * NH + wave] + eh;
        e = (e > 0.f) ? e : NEG_SLOPE * e;
        float w = __expf(e - mh);
        acc += w * hfeat[(size_t)src * HC + tid];
    }
    float o = acc * inv_s + bias[tid];
    out[(size_t)n * HC + tid] = fmaxf(o, 0.f);
}

// ---------------- mean pool + final linear ----------------
__global__ __launch_bounds__(256) void pool_sum(const float* __restrict__ h,
                                                const int* __restrict__ batch,
                                                float* __restrict__ sums) {
    int t  = threadIdx.x;
    int n0 = blockIdx.x * 128;
    if (n0 >= NN) return;
    int cur = batch[n0];
    float acc = 0.f;
    int nend = min(n0 + 128, NN);
    for (int n = n0; n < nend; ++n) {
        int g = batch[n];
        if (g != cur) {
            atomicAdd(&sums[cur * HC + t], acc);
            acc = 0.f; cur = g;
        }
        acc += h[(size_t)n * HC + t];
    }
    atomicAdd(&sums[cur * HC + t], acc);
}

__global__ void count_batch(const int* __restrict__ batch, int* __restrict__ gcnt) {
    int i = blockIdx.x * 256 + threadIdx.x;
    if (i < NN) atomicAdd(&gcnt[batch[i]], 1);
}

__global__ __launch_bounds__(256) void final_linear(const float* __restrict__ sums,
                                                    const int* __restrict__ gcnt,
                                                    const float* __restrict__ Wlin,
                                                    const float* __restrict__ blin,
                                                    float* __restrict__ out) {
    int idx = blockIdx.x * 256 + threadIdx.x;   // 0..1023
    if (idx >= NG * NOUT) return;
    int g = idx >> 4, o = idx & 15;
    float invc = 1.f / fmaxf((float)gcnt[g], 1.f);
    float acc = 0.f;
    for (int k = 0; k < HC; ++k) acc += sums[g * HC + k] * Wlin[k * NOUT + o];
    out[idx] = acc * invc + blin[o];
}

// ---------------- launch ----------------
extern "C" void kernel_launch(void* const* d_in, const int* in_sizes, int n_in,
                              void* d_out, int out_size, void* d_ws, size_t ws_size,
                              hipStream_t stream) {
    const float* x      = (const float*)d_in[0];
    const int*   ei     = (const int*)d_in[1];
    const int*   batch  = (const int*)d_in[2];
    const float* W1     = (const float*)d_in[3];
    const float* a_src1 = (const float*)d_in[4];
    const float* a_dst1 = (const float*)d_in[5];
    const float* b1     = (const float*)d_in[6];
    const float* W2     = (const float*)d_in[7];
    const float* a_src2 = (const float*)d_in[8];
    const float* a_dst2 = (const float*)d_in[9];
    const float* b2     = (const float*)d_in[10];
    const float* Wlin   = (const float*)d_in[11];
    const float* blin   = (const float*)d_in[12];
    float* out = (float*)d_out;

    char* p = (char*)d_ws;
    auto take = [&](size_t bytes) {
        char* r = p;
        p += (bytes + 255) & ~(size_t)255;
        return r;
    };
    float* bufT   = (float*)take((size_t)NN * HC * 4);
    float* bufH   = (float*)take((size_t)NN * HC * 4);
    float* es     = (float*)take((size_t)NN * NH * 4);
    float* ed     = (float*)take((size_t)NN * NH * 4);
    int*   cnt_n  = (int*)take((size_t)NN * 4);
    int*   rowptr = (int*)take((size_t)(NN + 1) * 4);
    int*   cursor = (int*)take((size_t)NN * 4);
    int*   csr    = (int*)take((size_t)ETOT * 4);
    float* sums   = (float*)take((size_t)NG * HC * 4);
    int*   gcnt   = (int*)take((size_t)NG * 4);

    hipMemsetAsync(cnt_n, 0, (size_t)NN * 4, stream);
    hipMemsetAsync(sums, 0, (size_t)NG * HC * 4, stream);
    hipMemsetAsync(gcnt, 0, (size_t)NG * 4, stream);

    count_dst<<<(ETOT + 255) / 256, 256, 0, stream>>>(ei, cnt_n);
    scan_kernel<<<1, 1024, 0, stream>>>(cnt_n, rowptr);
    copy_cursor<<<(NN + 255) / 256, 256, 0, stream>>>(rowptr, cursor);
    scatter_edges<<<(ETOT + 255) / 256, 256, 0, stream>>>(ei, cursor, csr);

    // layer 1
    gemm_f32<<<dim3(2, (NN + 127) / 128), 256, 0, stream>>>(x, W1, bufT, NN, FIN);
    attn_scores<<<(NN + 3) / 4, 256, 0, stream>>>(bufT, a_src1, a_dst1, es, ed);
    gat_aggregate<<<NN, 256, 0, stream>>>(bufT, es, ed, rowptr, csr, b1, bufH);

    // layer 2
    gemm_f32<<<dim3(2, (NN + 127) / 128), 256, 0, stream>>>(bufH, W2, bufT, NN, HC);
    attn_scores<<<(NN + 3) / 4, 256, 0, stream>>>(bufT, a_src2, a_dst2, es, ed);
    gat_aggregate<<<NN, 256, 0, stream>>>(bufT, es, ed, rowptr, csr, b2, bufH);

    // pool + head
    pool_sum<<<(NN + 127) / 128, 256, 0, stream>>>(bufH, batch, sums);
    count_batch<<<(NN + 255) / 256, 256, 0, stream>>>(batch, gcnt);
    final_linear<<<4, 256, 0, stream>>>(sums, gcnt, Wlin, blin, out);
}

// Round 2
// 1138.185 us; speedup vs baseline: 1.0164x; 1.0164x over previous
//
#include <hip/hip_runtime.h>

#define NN   50000
#define EE   800000
#define ETOT 850000   // EE + NN self loops
#define FIN  128
#define HC   256      // H*C
#define NH   4
#define CH   64
#define NG   64
#define NOUT 16
#define NEG_SLOPE 0.2f

// ---------------- online softmax combine (sentinel -1e30 avoids NaN) ----------
__device__ __forceinline__ void sm_combine(float& m, float& s, float om, float os) {
    float M = fmaxf(m, om);
    s = s * __expf(m - M) + os * __expf(om - M);
    m = M;
}

// ---------------- CSR build ----------------
__global__ void count_dst(const int* __restrict__ ei, int* __restrict__ cnt) {
    int i = blockIdx.x * 256 + threadIdx.x;
    if (i >= ETOT) return;
    int dst = (i < EE) ? ei[EE + i] : (i - EE);
    atomicAdd(&cnt[dst], 1);
}

__global__ __launch_bounds__(1024) void scan_kernel(const int* __restrict__ cnt,
                                                    int* __restrict__ rowptr) {
    __shared__ int lds[1024];
    __shared__ int carry_s;
    int tid = threadIdx.x;
    if (tid == 0) { carry_s = 0; rowptr[0] = 0; }
    __syncthreads();
    for (int base = 0; base < NN; base += 1024) {
        int i = base + tid;
        int v = (i < NN) ? cnt[i] : 0;
        lds[tid] = v;
        __syncthreads();
        for (int off = 1; off < 1024; off <<= 1) {
            int t = (tid >= off) ? lds[tid - off] : 0;
            __syncthreads();
            lds[tid] += t;
            __syncthreads();
        }
        int incl = lds[tid] + carry_s;
        if (i < NN) rowptr[i + 1] = incl;
        __syncthreads();
        if (tid == 1023) carry_s = incl;
        __syncthreads();
    }
}

__global__ void copy_cursor(const int* __restrict__ rowptr, int* __restrict__ cur) {
    int i = blockIdx.x * 256 + threadIdx.x;
    if (i < NN) cur[i] = rowptr[i];
}

__global__ void scatter_edges(const int* __restrict__ ei, int* __restrict__ cur,
                              int* __restrict__ csr_src) {
    int i = blockIdx.x * 256 + threadIdx.x;
    if (i >= ETOT) return;
    int src = (i < EE) ? ei[i] : (i - EE);
    int dst = (i < EE) ? ei[EE + i] : (i - EE);
    int pos = atomicAdd(&cur[dst], 1);
    csr_src[pos] = src;
}

// ---------------- f32 GEMM: C[M,256] = A[M,K] @ B[K,256] ----------------
__global__ __launch_bounds__(256) void gemm_f32(const float* __restrict__ A,
                                                const float* __restrict__ B,
                                                float* __restrict__ C,
                                                int M, int K) {
    __shared__ float As[16][128];   // transposed A tile [k][m]
    __shared__ float Bs[16][128];
    const int tid = threadIdx.x;
    const int tx = tid & 15, ty = tid >> 4;
    const int m0 = blockIdx.y * 128;
    const int n0 = blockIdx.x * 128;

    float acc[8][8];
#pragma unroll
    for (int i = 0; i < 8; ++i)
#pragma unroll
        for (int j = 0; j < 8; ++j) acc[i][j] = 0.f;

    const int lrow = tid >> 2;   // 0..63
    const int lq   = tid & 3;    // 0..3
    const int brow = tid >> 4;   // 0..15
    const int bq   = tid & 15;   // 0..15

    for (int kt = 0; kt < K; kt += 16) {
#pragma unroll
        for (int rr = 0; rr < 2; ++rr) {
            int row  = lrow + rr * 64;
            int grow = m0 + row;
            float4 v = make_float4(0.f, 0.f, 0.f, 0.f);
            if (grow < M) v = *(const float4*)&A[(size_t)grow * K + kt + lq * 4];
            As[lq * 4 + 0][row] = v.x;
            As[lq * 4 + 1][row] = v.y;
            As[lq * 4 + 2][row] = v.z;
            As[lq * 4 + 3][row] = v.w;
        }
        float4 bv0 = *(const float4*)&B[(size_t)(kt + brow) * HC + n0 + bq * 8];
        float4 bv1 = *(const float4*)&B[(size_t)(kt + brow) * HC + n0 + bq * 8 + 4];
        *(float4*)&Bs[brow][bq * 8]     = bv0;
        *(float4*)&Bs[brow][bq * 8 + 4] = bv1;
        __syncthreads();
#pragma unroll
        for (int k = 0; k < 16; ++k) {
            float4 a0 = *(const float4*)&As[k][ty * 8];
            float4 a1 = *(const float4*)&As[k][ty * 8 + 4];
            float4 b0 = *(const float4*)&Bs[k][tx * 8];
            float4 b1 = *(const float4*)&Bs[k][tx * 8 + 4];
            float av[8] = {a0.x, a0.y, a0.z, a0.w, a1.x, a1.y, a1.z, a1.w};
            float bw[8] = {b0.x, b0.y, b0.z, b0.w, b1.x, b1.y, b1.z, b1.w};
#pragma unroll
            for (int i = 0; i < 8; ++i)
#pragma unroll
                for (int j = 0; j < 8; ++j)
                    acc[i][j] = fmaf(av[i], bw[j], acc[i][j]);
        }
        __syncthreads();
    }
#pragma unroll
    for (int i = 0; i < 8; ++i) {
        int row = m0 + ty * 8 + i;
        if (row < M) {
            float4 o0 = make_float4(acc[i][0], acc[i][1], acc[i][2], acc[i][3]);
            float4 o1 = make_float4(acc[i][4], acc[i][5], acc[i][6], acc[i][7]);
            *(float4*)&C[(size_t)row * HC + n0 + tx * 8]     = o0;
            *(float4*)&C[(size_t)row * HC + n0 + tx * 8 + 4] = o1;
        }
    }
}

// ---------------- per-node attention scores ----------------
__global__ __launch_bounds__(256) void attn_scores(const float* __restrict__ h,
                                                   const float* __restrict__ a_src,
                                                   const float* __restrict__ a_dst,
                                                   float* __restrict__ es,
                                                   float* __restrict__ ed) {
    int node = blockIdx.x * 4 + (threadIdx.x >> 6);
    int lane = threadIdx.x & 63;
    if (node >= NN) return;
#pragma unroll
    for (int hh = 0; hh < NH; ++hh) {
        float v  = h[(size_t)node * HC + hh * CH + lane];
        float ps = v * a_src[hh * CH + lane];
        float pd = v * a_dst[hh * CH + lane];
#pragma unroll
        for (int off = 32; off > 0; off >>= 1) {
            ps += __shfl_xor(ps, off);
            pd += __shfl_xor(pd, off);
        }
        if (lane == 0) {
            es[node * NH + hh] = ps;
            ed[node * NH + hh] = pd;
        }
    }
}

// ---- softmax m,s per node, then normalized alpha per edge (block per node) --
__global__ __launch_bounds__(256) void softmax_alpha(const float* __restrict__ es,
                                                     const float* __restrict__ ed,
                                                     const int* __restrict__ rowptr,
                                                     const int* __restrict__ csr_src,
                                                     float* __restrict__ alpha) {
    const int n    = blockIdx.x;
    const int tid  = threadIdx.x;
    const int lane = tid & 63;
    const int wave = tid >> 6;
    const int start = rowptr[n];
    const int deg   = rowptr[n + 1] - start;

    float edn[NH];
#pragma unroll
    for (int h = 0; h < NH; ++h) edn[h] = ed[n * NH + h];

    float m[NH], s[NH];
#pragma unroll
    for (int h = 0; h < NH; ++h) { m[h] = -1e30f; s[h] = 0.f; }

    for (int j = tid; j < deg; j += 256) {
        int src = csr_src[start + j];
        float4 e4 = *(const float4*)&es[src * NH];
        float ev[NH] = {e4.x, e4.y, e4.z, e4.w};
#pragma unroll
        for (int h = 0; h < NH; ++h) {
            float e = ev[h] + edn[h];
            e = (e > 0.f) ? e : NEG_SLOPE * e;
            sm_combine(m[h], s[h], e, 1.0f);
        }
    }
#pragma unroll
    for (int h = 0; h < NH; ++h)
#pragma unroll
        for (int off = 32; off > 0; off >>= 1) {
            float om = __shfl_xor(m[h], off);
            float os = __shfl_xor(s[h], off);
            sm_combine(m[h], s[h], om, os);
        }
    __shared__ float rm[4][NH], rs[4][NH];
    __shared__ float fm[NH], fis[NH];
    if (lane == 0)
#pragma unroll
        for (int h = 0; h < NH; ++h) { rm[wave][h] = m[h]; rs[wave][h] = s[h]; }
    __syncthreads();
    if (tid < NH) {
        float M = rm[0][tid], S = rs[0][tid];
#pragma unroll
        for (int w = 1; w < 4; ++w) sm_combine(M, S, rm[w][tid], rs[w][tid]);
        fm[tid] = M; fis[tid] = 1.0f / S;
    }
    __syncthreads();

    float lm[NH], lis[NH];
#pragma unroll
    for (int h = 0; h < NH; ++h) { lm[h] = fm[h]; lis[h] = fis[h]; }

    // edge-parallel normalized alpha
    for (int j = tid; j < deg; j += 256) {
        int src = csr_src[start + j];
        float4 e4 = *(const float4*)&es[src * NH];
        float ev[NH] = {e4.x, e4.y, e4.z, e4.w};
        float4 av;
        float* ap = &av.x;
#pragma unroll
        for (int h = 0; h < NH; ++h) {
            float e = ev[h] + edn[h];
            e = (e > 0.f) ? e : NEG_SLOPE * e;
            ap[h] = __expf(e - lm[h]) * lis[h];
        }
        *(float4*)&alpha[(size_t)(start + j) * NH] = av;
    }
}

// ---------------- gather: one wave per node, float4 per lane ----------------
__global__ __launch_bounds__(256) void gat_gather(const float* __restrict__ hfeat,
                                                  const float* __restrict__ alpha,
                                                  const int* __restrict__ rowptr,
                                                  const int* __restrict__ csr_src,
                                                  const float* __restrict__ bias,
                                                  float* __restrict__ out) {
    const int node = blockIdx.x * 4 + (threadIdx.x >> 6);
    const int lane = threadIdx.x & 63;
    if (node >= NN) return;
    const int start = rowptr[node];
    const int deg   = rowptr[node + 1] - start;
    const int hsel  = lane >> 4;   // head for this lane's 4 channels

    float4 acc = make_float4(0.f, 0.f, 0.f, 0.f);
    int j = 0;
    for (; j + 1 < deg; j += 2) {
        int s0 = csr_src[start + j];
        int s1 = csr_src[start + j + 1];
        float a0 = alpha[(size_t)(start + j) * NH + hsel];
        float a1 = alpha[(size_t)(start + j + 1) * NH + hsel];
        float4 v0 = *(const float4*)&hfeat[(size_t)s0 * HC + lane * 4];
        float4 v1 = *(const float4*)&hfeat[(size_t)s1 * HC + lane * 4];
        acc.x = fmaf(a0, v0.x, acc.x);
        acc.y = fmaf(a0, v0.y, acc.y);
        acc.z = fmaf(a0, v0.z, acc.z);
        acc.w = fmaf(a0, v0.w, acc.w);
        acc.x = fmaf(a1, v1.x, acc.x);
        acc.y = fmaf(a1, v1.y, acc.y);
        acc.z = fmaf(a1, v1.z, acc.z);
        acc.w = fmaf(a1, v1.w, acc.w);
    }
    if (j < deg) {
        int s0 = csr_src[start + j];
        float a0 = alpha[(size_t)(start + j) * NH + hsel];
        float4 v0 = *(const float4*)&hfeat[(size_t)s0 * HC + lane * 4];
        acc.x = fmaf(a0, v0.x, acc.x);
        acc.y = fmaf(a0, v0.y, acc.y);
        acc.z = fmaf(a0, v0.z, acc.z);
        acc.w = fmaf(a0, v0.w, acc.w);
    }
    float4 b4 = *(const float4*)&bias[lane * 4];
    float4 o;
    o.x = fmaxf(acc.x + b4.x, 0.f);
    o.y = fmaxf(acc.y + b4.y, 0.f);
    o.z = fmaxf(acc.z + b4.z, 0.f);
    o.w = fmaxf(acc.w + b4.w, 0.f);
    *(float4*)&out[(size_t)node * HC + lane * 4] = o;
}

// ---------------- mean pool + final linear ----------------
__global__ __launch_bounds__(256) void pool_sum(const float* __restrict__ h,
                                                const int* __restrict__ batch,
                                                float* __restrict__ sums) {
    int t  = threadIdx.x;
    int n0 = blockIdx.x * 128;
    if (n0 >= NN) return;
    int cur = batch[n0];
    float acc = 0.f;
    int nend = min(n0 + 128, NN);
    for (int n = n0; n < nend; ++n) {
        int g = batch[n];
        if (g != cur) {
            atomicAdd(&sums[cur * HC + t], acc);
            acc = 0.f; cur = g;
        }
        acc += h[(size_t)n * HC + t];
    }
    atomicAdd(&sums[cur * HC + t], acc);
}

__global__ void count_batch(const int* __restrict__ batch, int* __restrict__ gcnt) {
    int i = blockIdx.x * 256 + threadIdx.x;
    if (i < NN) atomicAdd(&gcnt[batch[i]], 1);
}

__global__ __launch_bounds__(256) void final_linear(const float* __restrict__ sums,
                                                    const int* __restrict__ gcnt,
                                                    const float* __restrict__ Wlin,
                                                    const float* __restrict__ blin,
                                                    float* __restrict__ out) {
    int idx = blockIdx.x * 256 + threadIdx.x;   // 0..1023
    if (idx >= NG * NOUT) return;
    int g = idx >> 4, o = idx & 15;
    float invc = 1.f / fmaxf((float)gcnt[g], 1.f);
    float acc = 0.f;
    for (int k = 0; k < HC; ++k) acc += sums[g * HC + k] * Wlin[k * NOUT + o];
    out[idx] = acc * invc + blin[o];
}

// ---------------- launch ----------------
extern "C" void kernel_launch(void* const* d_in, const int* in_sizes, int n_in,
                              void* d_out, int out_size, void* d_ws, size_t ws_size,
                              hipStream_t stream) {
    const float* x      = (const float*)d_in[0];
    const int*   ei     = (const int*)d_in[1];
    const int*   batch  = (const int*)d_in[2];
    const float* W1     = (const float*)d_in[3];
    const float* a_src1 = (const float*)d_in[4];
    const float* a_dst1 = (const float*)d_in[5];
    const float* b1     = (const float*)d_in[6];
    const float* W2     = (const float*)d_in[7];
    const float* a_src2 = (const float*)d_in[8];
    const float* a_dst2 = (const float*)d_in[9];
    const float* b2     = (const float*)d_in[10];
    const float* Wlin   = (const float*)d_in[11];
    const float* blin   = (const float*)d_in[12];
    float* out = (float*)d_out;

    char* p = (char*)d_ws;
    auto take = [&](size_t bytes) {
        char* r = p;
        p += (bytes + 255) & ~(size_t)255;
        return r;
    };
    float* bufT   = (float*)take((size_t)NN * HC * 4);
    float* bufH   = (float*)take((size_t)NN * HC * 4);
    float* es     = (float*)take((size_t)NN * NH * 4);
    float* ed     = (float*)take((size_t)NN * NH * 4);
    int*   cnt_n  = (int*)take((size_t)NN * 4);
    int*   rowptr = (int*)take((size_t)(NN + 1) * 4);
    int*   cursor = (int*)take((size_t)NN * 4);
    int*   csr    = (int*)take((size_t)ETOT * 4);
    float* albuf  = (float*)take((size_t)ETOT * NH * 4);
    float* sums   = (float*)take((size_t)NG * HC * 4);
    int*   gcnt   = (int*)take((size_t)NG * 4);

    hipMemsetAsync(cnt_n, 0, (size_t)NN * 4, stream);
    hipMemsetAsync(sums, 0, (size_t)NG * HC * 4, stream);
    hipMemsetAsync(gcnt, 0, (size_t)NG * 4, stream);

    count_dst<<<(ETOT + 255) / 256, 256, 0, stream>>>(ei, cnt_n);
    scan_kernel<<<1, 1024, 0, stream>>>(cnt_n, rowptr);
    copy_cursor<<<(NN + 255) / 256, 256, 0, stream>>>(rowptr, cursor);
    scatter_edges<<<(ETOT + 255) / 256, 256, 0, stream>>>(ei, cursor, csr);

    // layer 1
    gemm_f32<<<dim3(2, (NN + 127) / 128), 256, 0, stream>>>(x, W1, bufT, NN, FIN);
    attn_scores<<<(NN + 3) / 4, 256, 0, stream>>>(bufT, a_src1, a_dst1, es, ed);
    softmax_alpha<<<NN, 256, 0, stream>>>(es, ed, rowptr, csr, albuf);
    gat_gather<<<(NN + 3) / 4, 256, 0, stream>>>(bufT, albuf, rowptr, csr, b1, bufH);

    // layer 2
    gemm_f32<<<dim3(2, (NN + 127) / 128), 256, 0, stream>>>(bufH, W2, bufT, NN, HC);
    attn_scores<<<(NN + 3) / 4, 256, 0, stream>>>(bufT, a_src2, a_dst2, es, ed);
    softmax_alpha<<<NN, 256, 0, stream>>>(es, ed, rowptr, csr, albuf);
    gat_gather<<<(NN + 3) / 4, 256, 0, stream>>>(bufT, albuf, rowptr, csr, b2, bufH);

    // pool + head
    pool_sum<<<(NN + 127) / 128, 256, 0, stream>>>(bufH, batch, sums);
    count_batch<<<(NN + 255) / 256, 256, 0, stream>>>(batch, gcnt);
    final_linear<<<4, 256, 0, stream>>>(sums, gcnt, Wlin, blin, out);
}

// Round 3
// 755.321 us; speedup vs baseline: 1.5316x; 1.5069x over previous
//
#include <hip/hip_runtime.h>

#define NN   50000
#define EE   800000
#define ETOT 850000   // EE + NN self loops
#define FIN  128
#define HC   256      // H*C
#define NH   4
#define CH   64
#define NG   64
#define NOUT 16
#define NEG_SLOPE 0.2f

// ---------------- online softmax combine (sentinel -1e30 avoids NaN) ----------
__device__ __forceinline__ void sm_combine(float& m, float& s, float om, float os) {
    float M = fmaxf(m, om);
    s = s * __expf(m - M) + os * __expf(om - M);
    m = M;
}

// ---------------- CSR build ----------------
__global__ void count_dst(const int* __restrict__ ei, int* __restrict__ cnt) {
    int i = blockIdx.x * 256 + threadIdx.x;
    if (i >= ETOT) return;
    int dst = (i < EE) ? ei[EE + i] : (i - EE);
    atomicAdd(&cnt[dst], 1);
}

__global__ __launch_bounds__(1024) void scan_kernel(const int* __restrict__ cnt,
                                                    int* __restrict__ rowptr) {
    __shared__ int lds[1024];
    __shared__ int carry_s;
    int tid = threadIdx.x;
    if (tid == 0) { carry_s = 0; rowptr[0] = 0; }
    __syncthreads();
    for (int base = 0; base < NN; base += 1024) {
        int i = base + tid;
        int v = (i < NN) ? cnt[i] : 0;
        lds[tid] = v;
        __syncthreads();
        for (int off = 1; off < 1024; off <<= 1) {
            int t = (tid >= off) ? lds[tid - off] : 0;
            __syncthreads();
            lds[tid] += t;
            __syncthreads();
        }
        int incl = lds[tid] + carry_s;
        if (i < NN) rowptr[i + 1] = incl;
        __syncthreads();
        if (tid == 1023) carry_s = incl;
        __syncthreads();
    }
}

__global__ void copy_cursor(const int* __restrict__ rowptr, int* __restrict__ cur) {
    int i = blockIdx.x * 256 + threadIdx.x;
    if (i < NN) cur[i] = rowptr[i];
}

__global__ void scatter_edges(const int* __restrict__ ei, int* __restrict__ cur,
                              int* __restrict__ csr_src) {
    int i = blockIdx.x * 256 + threadIdx.x;
    if (i >= ETOT) return;
    int src = (i < EE) ? ei[i] : (i - EE);
    int dst = (i < EE) ? ei[EE + i] : (i - EE);
    int pos = atomicAdd(&cur[dst], 1);
    csr_src[pos] = src;
}

// ---------------- f32 GEMM: C[M,256] = A[M,K] @ B[K,256] ----------------
__global__ __launch_bounds__(256) void gemm_f32(const float* __restrict__ A,
                                                const float* __restrict__ B,
                                                float* __restrict__ C,
                                                int M, int K) {
    __shared__ float As[16][128];   // transposed A tile [k][m]
    __shared__ float Bs[16][128];
    const int tid = threadIdx.x;
    const int tx = tid & 15, ty = tid >> 4;
    const int m0 = blockIdx.y * 128;
    const int n0 = blockIdx.x * 128;

    float acc[8][8];
#pragma unroll
    for (int i = 0; i < 8; ++i)
#pragma unroll
        for (int j = 0; j < 8; ++j) acc[i][j] = 0.f;

    const int lrow = tid >> 2;   // 0..63
    const int lq   = tid & 3;    // 0..3
    const int brow = tid >> 4;   // 0..15
    const int bq   = tid & 15;   // 0..15

    for (int kt = 0; kt < K; kt += 16) {
#pragma unroll
        for (int rr = 0; rr < 2; ++rr) {
            int row  = lrow + rr * 64;
            int grow = m0 + row;
            float4 v = make_float4(0.f, 0.f, 0.f, 0.f);
            if (grow < M) v = *(const float4*)&A[(size_t)grow * K + kt + lq * 4];
            As[lq * 4 + 0][row] = v.x;
            As[lq * 4 + 1][row] = v.y;
            As[lq * 4 + 2][row] = v.z;
            As[lq * 4 + 3][row] = v.w;
        }
        float4 bv0 = *(const float4*)&B[(size_t)(kt + brow) * HC + n0 + bq * 8];
        float4 bv1 = *(const float4*)&B[(size_t)(kt + brow) * HC + n0 + bq * 8 + 4];
        *(float4*)&Bs[brow][bq * 8]     = bv0;
        *(float4*)&Bs[brow][bq * 8 + 4] = bv1;
        __syncthreads();
#pragma unroll
        for (int k = 0; k < 16; ++k) {
            float4 a0 = *(const float4*)&As[k][ty * 8];
            float4 a1 = *(const float4*)&As[k][ty * 8 + 4];
            float4 b0 = *(const float4*)&Bs[k][tx * 8];
            float4 b1 = *(const float4*)&Bs[k][tx * 8 + 4];
            float av[8] = {a0.x, a0.y, a0.z, a0.w, a1.x, a1.y, a1.z, a1.w};
            float bw[8] = {b0.x, b0.y, b0.z, b0.w, b1.x, b1.y, b1.z, b1.w};
#pragma unroll
            for (int i = 0; i < 8; ++i)
#pragma unroll
                for (int j = 0; j < 8; ++j)
                    acc[i][j] = fmaf(av[i], bw[j], acc[i][j]);
        }
        __syncthreads();
    }
#pragma unroll
    for (int i = 0; i < 8; ++i) {
        int row = m0 + ty * 8 + i;
        if (row < M) {
            float4 o0 = make_float4(acc[i][0], acc[i][1], acc[i][2], acc[i][3]);
            float4 o1 = make_float4(acc[i][4], acc[i][5], acc[i][6], acc[i][7]);
            *(float4*)&C[(size_t)row * HC + n0 + tx * 8]     = o0;
            *(float4*)&C[(size_t)row * HC + n0 + tx * 8 + 4] = o1;
        }
    }
}

// ---------------- per-node attention scores ----------------
__global__ __launch_bounds__(256) void attn_scores(const float* __restrict__ h,
                                                   const float* __restrict__ a_src,
                                                   const float* __restrict__ a_dst,
                                                   float* __restrict__ es,
                                                   float* __restrict__ ed) {
    int node = blockIdx.x * 4 + (threadIdx.x >> 6);
    int lane = threadIdx.x & 63;
    if (node >= NN) return;
#pragma unroll
    for (int hh = 0; hh < NH; ++hh) {
        float v  = h[(size_t)node * HC + hh * CH + lane];
        float ps = v * a_src[hh * CH + lane];
        float pd = v * a_dst[hh * CH + lane];
#pragma unroll
        for (int off = 32; off > 0; off >>= 1) {
            ps += __shfl_xor(ps, off);
            pd += __shfl_xor(pd, off);
        }
        if (lane == 0) {
            es[node * NH + hh] = ps;
            ed[node * NH + hh] = pd;
        }
    }
}

// ---- softmax: wave per node, butterfly reduce, edge-strided alpha write ----
__global__ __launch_bounds__(256) void softmax_alpha(const float* __restrict__ es,
                                                     const float* __restrict__ ed,
                                                     const int* __restrict__ rowptr,
                                                     const int* __restrict__ csr_src,
                                                     float* __restrict__ alpha) {
    const int node = blockIdx.x * 4 + (threadIdx.x >> 6);
    const int lane = threadIdx.x & 63;
    if (node >= NN) return;
    const int start = rowptr[node];
    const int deg   = rowptr[node + 1] - start;

    float4 ed4 = *(const float4*)&ed[node * NH];
    float edn[NH] = {ed4.x, ed4.y, ed4.z, ed4.w};

    float m[NH], s[NH];
#pragma unroll
    for (int h = 0; h < NH; ++h) { m[h] = -1e30f; s[h] = 0.f; }

    for (int j = lane; j < deg; j += 64) {
        int src = csr_src[start + j];
        float4 e4 = *(const float4*)&es[src * NH];
        float ev[NH] = {e4.x, e4.y, e4.z, e4.w};
#pragma unroll
        for (int h = 0; h < NH; ++h) {
            float e = ev[h] + edn[h];
            e = (e > 0.f) ? e : NEG_SLOPE * e;
            sm_combine(m[h], s[h], e, 1.0f);
        }
    }
    // full-wave butterfly: every lane ends with the node-wide (m,s)
#pragma unroll
    for (int h = 0; h < NH; ++h)
#pragma unroll
        for (int off = 32; off > 0; off >>= 1) {
            float om = __shfl_xor(m[h], off);
            float os = __shfl_xor(s[h], off);
            sm_combine(m[h], s[h], om, os);
        }
    float is[NH];
#pragma unroll
    for (int h = 0; h < NH; ++h) is[h] = 1.0f / s[h];

    for (int j = lane; j < deg; j += 64) {
        int src = csr_src[start + j];
        float4 e4 = *(const float4*)&es[src * NH];
        float ev[NH] = {e4.x, e4.y, e4.z, e4.w};
        float4 av;
        float* ap = &av.x;
#pragma unroll
        for (int h = 0; h < NH; ++h) {
            float e = ev[h] + edn[h];
            e = (e > 0.f) ? e : NEG_SLOPE * e;
            ap[h] = __expf(e - m[h]) * is[h];
        }
        *(float4*)&alpha[(size_t)(start + j) * NH] = av;
    }
}

// ---------------- gather: one wave per node, float4 per lane ----------------
__global__ __launch_bounds__(256) void gat_gather(const float* __restrict__ hfeat,
                                                  const float* __restrict__ alpha,
                                                  const int* __restrict__ rowptr,
                                                  const int* __restrict__ csr_src,
                                                  const float* __restrict__ bias,
                                                  float* __restrict__ out) {
    const int node = blockIdx.x * 4 + (threadIdx.x >> 6);
    const int lane = threadIdx.x & 63;
    if (node >= NN) return;
    const int start = rowptr[node];
    const int deg   = rowptr[node + 1] - start;
    const int hsel  = lane >> 4;   // head for this lane's 4 channels

    float4 acc = make_float4(0.f, 0.f, 0.f, 0.f);
    int j = 0;
    for (; j + 1 < deg; j += 2) {
        int s0 = csr_src[start + j];
        int s1 = csr_src[start + j + 1];
        float a0 = alpha[(size_t)(start + j) * NH + hsel];
        float a1 = alpha[(size_t)(start + j + 1) * NH + hsel];
        float4 v0 = *(const float4*)&hfeat[(size_t)s0 * HC + lane * 4];
        float4 v1 = *(const float4*)&hfeat[(size_t)s1 * HC + lane * 4];
        acc.x = fmaf(a0, v0.x, acc.x);
        acc.y = fmaf(a0, v0.y, acc.y);
        acc.z = fmaf(a0, v0.z, acc.z);
        acc.w = fmaf(a0, v0.w, acc.w);
        acc.x = fmaf(a1, v1.x, acc.x);
        acc.y = fmaf(a1, v1.y, acc.y);
        acc.z = fmaf(a1, v1.z, acc.z);
        acc.w = fmaf(a1, v1.w, acc.w);
    }
    if (j < deg) {
        int s0 = csr_src[start + j];
        float a0 = alpha[(size_t)(start + j) * NH + hsel];
        float4 v0 = *(const float4*)&hfeat[(size_t)s0 * HC + lane * 4];
        acc.x = fmaf(a0, v0.x, acc.x);
        acc.y = fmaf(a0, v0.y, acc.y);
        acc.z = fmaf(a0, v0.z, acc.z);
        acc.w = fmaf(a0, v0.w, acc.w);
    }
    float4 b4 = *(const float4*)&bias[lane * 4];
    float4 o;
    o.x = fmaxf(acc.x + b4.x, 0.f);
    o.y = fmaxf(acc.y + b4.y, 0.f);
    o.z = fmaxf(acc.z + b4.z, 0.f);
    o.w = fmaxf(acc.w + b4.w, 0.f);
    *(float4*)&out[(size_t)node * HC + lane * 4] = o;
}

// ---------------- mean pool + final linear ----------------
__global__ __launch_bounds__(256) void pool_sum(const float* __restrict__ h,
                                                const int* __restrict__ batch,
                                                float* __restrict__ sums) {
    int t  = threadIdx.x;
    int n0 = blockIdx.x * 128;
    if (n0 >= NN) return;
    int cur = batch[n0];
    float acc = 0.f;
    int nend = min(n0 + 128, NN);
    for (int n = n0; n < nend; ++n) {
        int g = batch[n];
        if (g != cur) {
            atomicAdd(&sums[cur * HC + t], acc);
            acc = 0.f; cur = g;
        }
        acc += h[(size_t)n * HC + t];
    }
    atomicAdd(&sums[cur * HC + t], acc);
}

// ---- group bounds from sorted batch: no atomics ----
__global__ void batch_bounds(const int* __restrict__ batch,
                             int* __restrict__ beg, int* __restrict__ end) {
    int i = blockIdx.x * 256 + threadIdx.x;
    if (i >= NN) return;
    int g = batch[i];
    if (i == 0      || batch[i - 1] != g) beg[g] = i;
    if (i == NN - 1 || batch[i + 1] != g) end[g] = i + 1;
}

__global__ __launch_bounds__(256) void final_linear(const float* __restrict__ sums,
                                                    const int* __restrict__ beg,
                                                    const int* __restrict__ end,
                                                    const float* __restrict__ Wlin,
                                                    const float* __restrict__ blin,
                                                    float* __restrict__ out) {
    int idx = blockIdx.x * 256 + threadIdx.x;   // 0..1023
    if (idx >= NG * NOUT) return;
    int g = idx >> 4, o = idx & 15;
    float cnt = (float)(end[g] - beg[g]);
    float invc = 1.f / fmaxf(cnt, 1.f);
    float acc = 0.f;
    for (int k = 0; k < HC; ++k) acc += sums[g * HC + k] * Wlin[k * NOUT + o];
    out[idx] = acc * invc + blin[o];
}

// ---------------- launch ----------------
extern "C" void kernel_launch(void* const* d_in, const int* in_sizes, int n_in,
                              void* d_out, int out_size, void* d_ws, size_t ws_size,
                              hipStream_t stream) {
    const float* x      = (const float*)d_in[0];
    const int*   ei     = (const int*)d_in[1];
    const int*   batch  = (const int*)d_in[2];
    const float* W1     = (const float*)d_in[3];
    const float* a_src1 = (const float*)d_in[4];
    const float* a_dst1 = (const float*)d_in[5];
    const float* b1     = (const float*)d_in[6];
    const float* W2     = (const float*)d_in[7];
    const float* a_src2 = (const float*)d_in[8];
    const float* a_dst2 = (const float*)d_in[9];
    const float* b2     = (const float*)d_in[10];
    const float* Wlin   = (const float*)d_in[11];
    const float* blin   = (const float*)d_in[12];
    float* out = (float*)d_out;

    char* p = (char*)d_ws;
    auto take = [&](size_t bytes) {
        char* r = p;
        p += (bytes + 255) & ~(size_t)255;
        return r;
    };
    float* bufT   = (float*)take((size_t)NN * HC * 4);
    float* bufH   = (float*)take((size_t)NN * HC * 4);
    float* es     = (float*)take((size_t)NN * NH * 4);
    float* ed     = (float*)take((size_t)NN * NH * 4);
    int*   cnt_n  = (int*)take((size_t)NN * 4);
    int*   rowptr = (int*)take((size_t)(NN + 1) * 4);
    int*   cursor = (int*)take((size_t)NN * 4);
    int*   csr    = (int*)take((size_t)ETOT * 4);
    float* albuf  = (float*)take((size_t)ETOT * NH * 4);
    float* sums   = (float*)take((size_t)NG * HC * 4);
    int*   gbeg   = (int*)take((size_t)NG * 4);
    int*   gend   = (int*)take((size_t)NG * 4);

    hipMemsetAsync(cnt_n, 0, (size_t)NN * 4, stream);
    hipMemsetAsync(sums, 0, (size_t)NG * HC * 4, stream);
    hipMemsetAsync(gbeg, 0, (size_t)NG * 4, stream);
    hipMemsetAsync(gend, 0, (size_t)NG * 4, stream);

    count_dst<<<(ETOT + 255) / 256, 256, 0, stream>>>(ei, cnt_n);
    scan_kernel<<<1, 1024, 0, stream>>>(cnt_n, rowptr);
    copy_cursor<<<(NN + 255) / 256, 256, 0, stream>>>(rowptr, cursor);
    scatter_edges<<<(ETOT + 255) / 256, 256, 0, stream>>>(ei, cursor, csr);

    // layer 1
    gemm_f32<<<dim3(2, (NN + 127) / 128), 256, 0, stream>>>(x, W1, bufT, NN, FIN);
    attn_scores<<<(NN + 3) / 4, 256, 0, stream>>>(bufT, a_src1, a_dst1, es, ed);
    softmax_alpha<<<(NN + 3) / 4, 256, 0, stream>>>(es, ed, rowptr, csr, albuf);
    gat_gather<<<(NN + 3) / 4, 256, 0, stream>>>(bufT, albuf, rowptr, csr, b1, bufH);

    // layer 2
    gemm_f32<<<dim3(2, (NN + 127) / 128), 256, 0, stream>>>(bufH, W2, bufT, NN, HC);
    attn_scores<<<(NN + 3) / 4, 256, 0, stream>>>(bufT, a_src2, a_dst2, es, ed);
    softmax_alpha<<<(NN + 3) / 4, 256, 0, stream>>>(es, ed, rowptr, csr, albuf);
    gat_gather<<<(NN + 3) / 4, 256, 0, stream>>>(bufT, albuf, rowptr, csr, b2, bufH);

    // pool + head
    pool_sum<<<(NN + 127) / 128, 256, 0, stream>>>(bufH, batch, sums);
    batch_bounds<<<(NN + 255) / 256, 256, 0, stream>>>(batch, gbeg, gend);
    final_linear<<<4, 256, 0, stream>>>(sums, gbeg, gend, Wlin, blin, out);
}

// Round 4
// 642.650 us; speedup vs baseline: 1.8001x; 1.1753x over previous
//
#include <hip/hip_runtime.h>
#include <hip/hip_fp16.h>

#define NN   50000
#define EE   800000
#define ETOT 850000   // EE + NN self loops
#define FIN  128
#define HC   256      // H*C
#define NH   4
#define CH   64
#define NG   64
#define NOUT 16
#define NEG_SLOPE 0.2f

// ---------------- online softmax combine (sentinel -1e30 avoids NaN) ----------
__device__ __forceinline__ void sm_combine(float& m, float& s, float om, float os) {
    float M = fmaxf(m, om);
    s = s * __expf(m - M) + os * __expf(om - M);
    m = M;
}

// ---------------- CSR build ----------------
__global__ void count_dst(const int* __restrict__ ei, int* __restrict__ cnt) {
    int i = blockIdx.x * 256 + threadIdx.x;
    if (i >= ETOT) return;
    int dst = (i < EE) ? ei[EE + i] : (i - EE);
    atomicAdd(&cnt[dst], 1);
}

// one-pass scan: per-thread serial sum -> block Kogge-Stone -> serial prefix
__global__ __launch_bounds__(1024) void scan_kernel(const int* __restrict__ cnt,
                                                    int* __restrict__ rowptr) {
    const int CHUNK = (NN + 1023) / 1024;   // 49
    const int tid   = threadIdx.x;
    const int begin = tid * CHUNK;
    const int endi  = (begin + CHUNK < NN) ? begin + CHUNK : NN;
    int sum = 0;
    for (int i = begin; i < endi; ++i) sum += cnt[i];
    __shared__ int lds[1024];
    lds[tid] = sum;
    __syncthreads();
    for (int off = 1; off < 1024; off <<= 1) {
        int t = (tid >= off) ? lds[tid - off] : 0;
        __syncthreads();
        lds[tid] += t;
        __syncthreads();
    }
    int run = lds[tid] - sum;   // exclusive prefix
    for (int i = begin; i < endi; ++i) { rowptr[i] = run; run += cnt[i]; }
    if (tid == 1023) rowptr[NN] = run;
}

__global__ void copy_cursor(const int* __restrict__ rowptr, int* __restrict__ cur) {
    int i = blockIdx.x * 256 + threadIdx.x;
    if (i < NN) cur[i] = rowptr[i];
}

__global__ void scatter_edges(const int* __restrict__ ei, int* __restrict__ cur,
                              int* __restrict__ csr_src) {
    int i = blockIdx.x * 256 + threadIdx.x;
    if (i >= ETOT) return;
    int src = (i < EE) ? ei[i] : (i - EE);
    int dst = (i < EE) ? ei[EE + i] : (i - EE);
    int pos = atomicAdd(&cur[dst], 1);
    csr_src[pos] = src;
}

// ---- f32 GEMM: C[M,256] = A[M,K] @ B[K,256]; also writes fp16 copy C16 ----
__global__ __launch_bounds__(256) void gemm_f32(const float* __restrict__ A,
                                                const float* __restrict__ B,
                                                float* __restrict__ C,
                                                __half* __restrict__ C16,
                                                int M, int K) {
    __shared__ float As[16][128];   // transposed A tile [k][m]
    __shared__ float Bs[16][128];
    const int tid = threadIdx.x;
    const int tx = tid & 15, ty = tid >> 4;
    const int m0 = blockIdx.y * 128;
    const int n0 = blockIdx.x * 128;

    float acc[8][8];
#pragma unroll
    for (int i = 0; i < 8; ++i)
#pragma unroll
        for (int j = 0; j < 8; ++j) acc[i][j] = 0.f;

    const int lrow = tid >> 2;   // 0..63
    const int lq   = tid & 3;    // 0..3
    const int brow = tid >> 4;   // 0..15
    const int bq   = tid & 15;   // 0..15

    for (int kt = 0; kt < K; kt += 16) {
#pragma unroll
        for (int rr = 0; rr < 2; ++rr) {
            int row  = lrow + rr * 64;
            int grow = m0 + row;
            float4 v = make_float4(0.f, 0.f, 0.f, 0.f);
            if (grow < M) v = *(const float4*)&A[(size_t)grow * K + kt + lq * 4];
            As[lq * 4 + 0][row] = v.x;
            As[lq * 4 + 1][row] = v.y;
            As[lq * 4 + 2][row] = v.z;
            As[lq * 4 + 3][row] = v.w;
        }
        float4 bv0 = *(const float4*)&B[(size_t)(kt + brow) * HC + n0 + bq * 8];
        float4 bv1 = *(const float4*)&B[(size_t)(kt + brow) * HC + n0 + bq * 8 + 4];
        *(float4*)&Bs[brow][bq * 8]     = bv0;
        *(float4*)&Bs[brow][bq * 8 + 4] = bv1;
        __syncthreads();
#pragma unroll
        for (int k = 0; k < 16; ++k) {
            float4 a0 = *(const float4*)&As[k][ty * 8];
            float4 a1 = *(const float4*)&As[k][ty * 8 + 4];
            float4 b0 = *(const float4*)&Bs[k][tx * 8];
            float4 b1 = *(const float4*)&Bs[k][tx * 8 + 4];
            float av[8] = {a0.x, a0.y, a0.z, a0.w, a1.x, a1.y, a1.z, a1.w};
            float bw[8] = {b0.x, b0.y, b0.z, b0.w, b1.x, b1.y, b1.z, b1.w};
#pragma unroll
            for (int i = 0; i < 8; ++i)
#pragma unroll
                for (int j = 0; j < 8; ++j)
                    acc[i][j] = fmaf(av[i], bw[j], acc[i][j]);
        }
        __syncthreads();
    }
#pragma unroll
    for (int i = 0; i < 8; ++i) {
        int row = m0 + ty * 8 + i;
        if (row < M) {
            float4 o0 = make_float4(acc[i][0], acc[i][1], acc[i][2], acc[i][3]);
            float4 o1 = make_float4(acc[i][4], acc[i][5], acc[i][6], acc[i][7]);
            *(float4*)&C[(size_t)row * HC + n0 + tx * 8]     = o0;
            *(float4*)&C[(size_t)row * HC + n0 + tx * 8 + 4] = o1;
            __half hb[8];
#pragma unroll
            for (int j = 0; j < 8; ++j) hb[j] = __float2half(acc[i][j]);
            *(uint4*)&C16[(size_t)row * HC + n0 + tx * 8] = *(uint4*)hb;
        }
    }
}

// ---------------- per-node attention scores ----------------
__global__ __launch_bounds__(256) void attn_scores(const float* __restrict__ h,
                                                   const float* __restrict__ a_src,
                                                   const float* __restrict__ a_dst,
                                                   float* __restrict__ es,
                                                   float* __restrict__ ed) {
    int node = blockIdx.x * 4 + (threadIdx.x >> 6);
    int lane = threadIdx.x & 63;
    if (node >= NN) return;
#pragma unroll
    for (int hh = 0; hh < NH; ++hh) {
        float v  = h[(size_t)node * HC + hh * CH + lane];
        float ps = v * a_src[hh * CH + lane];
        float pd = v * a_dst[hh * CH + lane];
#pragma unroll
        for (int off = 32; off > 0; off >>= 1) {
            ps += __shfl_xor(ps, off);
            pd += __shfl_xor(pd, off);
        }
        if (lane == 0) {
            es[node * NH + hh] = ps;
            ed[node * NH + hh] = pd;
        }
    }
}

// ---- softmax: wave per node, butterfly reduce, edge-strided alpha write ----
__global__ __launch_bounds__(256) void softmax_alpha(const float* __restrict__ es,
                                                     const float* __restrict__ ed,
                                                     const int* __restrict__ rowptr,
                                                     const int* __restrict__ csr_src,
                                                     float* __restrict__ alpha) {
    const int node = blockIdx.x * 4 + (threadIdx.x >> 6);
    const int lane = threadIdx.x & 63;
    if (node >= NN) return;
    const int start = rowptr[node];
    const int deg   = rowptr[node + 1] - start;

    float4 ed4 = *(const float4*)&ed[node * NH];
    float edn[NH] = {ed4.x, ed4.y, ed4.z, ed4.w};

    float m[NH], s[NH];
#pragma unroll
    for (int h = 0; h < NH; ++h) { m[h] = -1e30f; s[h] = 0.f; }

    for (int j = lane; j < deg; j += 64) {
        int src = csr_src[start + j];
        float4 e4 = *(const float4*)&es[src * NH];
        float ev[NH] = {e4.x, e4.y, e4.z, e4.w};
#pragma unroll
        for (int h = 0; h < NH; ++h) {
            float e = ev[h] + edn[h];
            e = (e > 0.f) ? e : NEG_SLOPE * e;
            sm_combine(m[h], s[h], e, 1.0f);
        }
    }
#pragma unroll
    for (int h = 0; h < NH; ++h)
#pragma unroll
        for (int off = 32; off > 0; off >>= 1) {
            float om = __shfl_xor(m[h], off);
            float os = __shfl_xor(s[h], off);
            sm_combine(m[h], s[h], om, os);
        }
    float is[NH];
#pragma unroll
    for (int h = 0; h < NH; ++h) is[h] = 1.0f / s[h];

    for (int j = lane; j < deg; j += 64) {
        int src = csr_src[start + j];
        float4 e4 = *(const float4*)&es[src * NH];
        float ev[NH] = {e4.x, e4.y, e4.z, e4.w};
        float4 av;
        float* ap = &av.x;
#pragma unroll
        for (int h = 0; h < NH; ++h) {
            float e = ev[h] + edn[h];
            e = (e > 0.f) ? e : NEG_SLOPE * e;
            ap[h] = __expf(e - m[h]) * is[h];
        }
        *(float4*)&alpha[(size_t)(start + j) * NH] = av;
    }
}

// ------- gather: one wave per node, fp16 features, 4 ch per lane -------
__global__ __launch_bounds__(256) void gat_gather(const __half* __restrict__ hfeat,
                                                  const float* __restrict__ alpha,
                                                  const int* __restrict__ rowptr,
                                                  const int* __restrict__ csr_src,
                                                  const float* __restrict__ bias,
                                                  float* __restrict__ out) {
    const int node = blockIdx.x * 4 + (threadIdx.x >> 6);
    const int lane = threadIdx.x & 63;
    if (node >= NN) return;
    const int start = rowptr[node];
    const int deg   = rowptr[node + 1] - start;
    const int hsel  = lane >> 4;   // head for this lane's 4 channels

    float4 acc = make_float4(0.f, 0.f, 0.f, 0.f);
    int j = 0;
    for (; j + 1 < deg; j += 2) {
        int s0 = csr_src[start + j];
        int s1 = csr_src[start + j + 1];
        float a0 = alpha[(size_t)(start + j) * NH + hsel];
        float a1 = alpha[(size_t)(start + j + 1) * NH + hsel];
        uint2 r0 = *(const uint2*)&hfeat[(size_t)s0 * HC + lane * 4];
        uint2 r1 = *(const uint2*)&hfeat[(size_t)s1 * HC + lane * 4];
        float2 f0a = __half22float2(*reinterpret_cast<__half2*>(&r0.x));
        float2 f0b = __half22float2(*reinterpret_cast<__half2*>(&r0.y));
        float2 f1a = __half22float2(*reinterpret_cast<__half2*>(&r1.x));
        float2 f1b = __half22float2(*reinterpret_cast<__half2*>(&r1.y));
        acc.x = fmaf(a0, f0a.x, acc.x);
        acc.y = fmaf(a0, f0a.y, acc.y);
        acc.z = fmaf(a0, f0b.x, acc.z);
        acc.w = fmaf(a0, f0b.y, acc.w);
        acc.x = fmaf(a1, f1a.x, acc.x);
        acc.y = fmaf(a1, f1a.y, acc.y);
        acc.z = fmaf(a1, f1b.x, acc.z);
        acc.w = fmaf(a1, f1b.y, acc.w);
    }
    if (j < deg) {
        int s0 = csr_src[start + j];
        float a0 = alpha[(size_t)(start + j) * NH + hsel];
        uint2 r0 = *(const uint2*)&hfeat[(size_t)s0 * HC + lane * 4];
        float2 f0a = __half22float2(*reinterpret_cast<__half2*>(&r0.x));
        float2 f0b = __half22float2(*reinterpret_cast<__half2*>(&r0.y));
        acc.x = fmaf(a0, f0a.x, acc.x);
        acc.y = fmaf(a0, f0a.y, acc.y);
        acc.z = fmaf(a0, f0b.x, acc.z);
        acc.w = fmaf(a0, f0b.y, acc.w);
    }
    float4 b4 = *(const float4*)&bias[lane * 4];
    float4 o;
    o.x = fmaxf(acc.x + b4.x, 0.f);
    o.y = fmaxf(acc.y + b4.y, 0.f);
    o.z = fmaxf(acc.z + b4.z, 0.f);
    o.w = fmaxf(acc.w + b4.w, 0.f);
    *(float4*)&out[(size_t)node * HC + lane * 4] = o;
}

// ---------------- mean pool + final linear ----------------
__global__ __launch_bounds__(256) void pool_sum(const float* __restrict__ h,
                                                const int* __restrict__ batch,
                                                float* __restrict__ sums) {
    int t  = threadIdx.x;
    int n0 = blockIdx.x * 128;
    if (n0 >= NN) return;
    int cur = batch[n0];
    float acc = 0.f;
    int nend = min(n0 + 128, NN);
    for (int n = n0; n < nend; ++n) {
        int g = batch[n];
        if (g != cur) {
            atomicAdd(&sums[cur * HC + t], acc);
            acc = 0.f; cur = g;
        }
        acc += h[(size_t)n * HC + t];
    }
    atomicAdd(&sums[cur * HC + t], acc);
}

// ---- group bounds from sorted batch: no atomics ----
__global__ void batch_bounds(const int* __restrict__ batch,
                             int* __restrict__ beg, int* __restrict__ end) {
    int i = blockIdx.x * 256 + threadIdx.x;
    if (i >= NN) return;
    int g = batch[i];
    if (i == 0      || batch[i - 1] != g) beg[g] = i;
    if (i == NN - 1 || batch[i + 1] != g) end[g] = i + 1;
}

__global__ __launch_bounds__(256) void final_linear(const float* __restrict__ sums,
                                                    const int* __restrict__ beg,
                                                    const int* __restrict__ end,
                                                    const float* __restrict__ Wlin,
                                                    const float* __restrict__ blin,
                                                    float* __restrict__ out) {
    int idx = blockIdx.x * 256 + threadIdx.x;   // 0..1023
    if (idx >= NG * NOUT) return;
    int g = idx >> 4, o = idx & 15;
    float cnt = (float)(end[g] - beg[g]);
    float invc = 1.f / fmaxf(cnt, 1.f);
    float acc = 0.f;
    for (int k = 0; k < HC; ++k) acc += sums[g * HC + k] * Wlin[k * NOUT + o];
    out[idx] = acc * invc + blin[o];
}

// ---------------- launch ----------------
extern "C" void kernel_launch(void* const* d_in, const int* in_sizes, int n_in,
                              void* d_out, int out_size, void* d_ws, size_t ws_size,
                              hipStream_t stream) {
    const float* x      = (const float*)d_in[0];
    const int*   ei     = (const int*)d_in[1];
    const int*   batch  = (const int*)d_in[2];
    const float* W1     = (const float*)d_in[3];
    const float* a_src1 = (const float*)d_in[4];
    const float* a_dst1 = (const float*)d_in[5];
    const float* b1     = (const float*)d_in[6];
    const float* W2     = (const float*)d_in[7];
    const float* a_src2 = (const float*)d_in[8];
    const float* a_dst2 = (const float*)d_in[9];
    const float* b2     = (const float*)d_in[10];
    const float* Wlin   = (const float*)d_in[11];
    const float* blin   = (const float*)d_in[12];
    float* out = (float*)d_out;

    char* p = (char*)d_ws;
    auto take = [&](size_t bytes) {
        char* r = p;
        p += (bytes + 255) & ~(size_t)255;
        return r;
    };
    float*  bufT   = (float*)take((size_t)NN * HC * 4);
    float*  bufH   = (float*)take((size_t)NN * HC * 4);
    __half* bufT16 = (__half*)take((size_t)NN * HC * 2);
    float*  es     = (float*)take((size_t)NN * NH * 4);
    float*  ed     = (float*)take((size_t)NN * NH * 4);
    int*    cnt_n  = (int*)take((size_t)NN * 4);
    int*    rowptr = (int*)take((size_t)(NN + 1) * 4);
    int*    cursor = (int*)take((size_t)NN * 4);
    int*    csr    = (int*)take((size_t)ETOT * 4);
    float*  albuf  = (float*)take((size_t)ETOT * NH * 4);
    float*  sums   = (float*)take((size_t)NG * HC * 4);
    int*    gbeg   = (int*)take((size_t)NG * 4);
    int*    gend   = (int*)take((size_t)NG * 4);

    hipMemsetAsync(cnt_n, 0, (size_t)NN * 4, stream);
    hipMemsetAsync(sums, 0, (size_t)NG * HC * 4, stream);
    hipMemsetAsync(gbeg, 0, (size_t)NG * 4, stream);
    hipMemsetAsync(gend, 0, (size_t)NG * 4, stream);

    count_dst<<<(ETOT + 255) / 256, 256, 0, stream>>>(ei, cnt_n);
    scan_kernel<<<1, 1024, 0, stream>>>(cnt_n, rowptr);
    copy_cursor<<<(NN + 255) / 256, 256, 0, stream>>>(rowptr, cursor);
    scatter_edges<<<(ETOT + 255) / 256, 256, 0, stream>>>(ei, cursor, csr);

    // layer 1
    gemm_f32<<<dim3(2, (NN + 127) / 128), 256, 0, stream>>>(x, W1, bufT, bufT16, NN, FIN);
    attn_scores<<<(NN + 3) / 4, 256, 0, stream>>>(bufT, a_src1, a_dst1, es, ed);
    softmax_alpha<<<(NN + 3) / 4, 256, 0, stream>>>(es, ed, rowptr, csr, albuf);
    gat_gather<<<(NN + 3) / 4, 256, 0, stream>>>(bufT16, albuf, rowptr, csr, b1, bufH);

    // layer 2
    gemm_f32<<<dim3(2, (NN + 127) / 128), 256, 0, stream>>>(bufH, W2, bufT, bufT16, NN, HC);
    attn_scores<<<(NN + 3) / 4, 256, 0, stream>>>(bufT, a_src2, a_dst2, es, ed);
    softmax_alpha<<<(NN + 3) / 4, 256, 0, stream>>>(es, ed, rowptr, csr, albuf);
    gat_gather<<<(NN + 3) / 4, 256, 0, stream>>>(bufT16, albuf, rowptr, csr, b2, bufH);

    // pool + head
    pool_sum<<<(NN + 127) / 128, 256, 0, stream>>>(bufH, batch, sums);
    batch_bounds<<<(NN + 255) / 256, 256, 0, stream>>>(batch, gbeg, gend);
    final_linear<<<4, 256, 0, stream>>>(sums, gbeg, gend, Wlin, blin, out);
}

// Round 5
// 554.898 us; speedup vs baseline: 2.0848x; 1.1581x over previous
//
#include <hip/hip_runtime.h>
#include <hip/hip_fp16.h>

#define NN   50000
#define EE   800000
#define ETOT 850000   // EE + NN self loops
#define FIN  128
#define HC   256      // H*C
#define NH   4
#define CH   64
#define NG   64
#define NOUT 16
#define NEG_SLOPE 0.2f

typedef _Float16 f16x8 __attribute__((ext_vector_type(8)));
typedef float    f32x4 __attribute__((ext_vector_type(4)));

// ---------------- online softmax combine (sentinel -1e30 avoids NaN) ----------
__device__ __forceinline__ void sm_combine(float& m, float& s, float om, float os) {
    float M = fmaxf(m, om);
    s = s * __expf(m - M) + os * __expf(om - M);
    m = M;
}

// ---------------- CSR build ----------------
__global__ void count_dst(const int* __restrict__ ei, int* __restrict__ cnt) {
    int i = blockIdx.x * 256 + threadIdx.x;
    if (i >= ETOT) return;
    int dst = (i < EE) ? ei[EE + i] : (i - EE);
    atomicAdd(&cnt[dst], 1);
}

// one-pass scan: per-thread serial sum -> block Kogge-Stone -> serial prefix
__global__ __launch_bounds__(1024) void scan_kernel(const int* __restrict__ cnt,
                                                    int* __restrict__ rowptr) {
    const int CHUNK = (NN + 1023) / 1024;   // 49
    const int tid   = threadIdx.x;
    const int begin = tid * CHUNK;
    const int endi  = (begin + CHUNK < NN) ? begin + CHUNK : NN;
    int sum = 0;
    for (int i = begin; i < endi; ++i) sum += cnt[i];
    __shared__ int lds[1024];
    lds[tid] = sum;
    __syncthreads();
    for (int off = 1; off < 1024; off <<= 1) {
        int t = (tid >= off) ? lds[tid - off] : 0;
        __syncthreads();
        lds[tid] += t;
        __syncthreads();
    }
    int run = lds[tid] - sum;   // exclusive prefix
    for (int i = begin; i < endi; ++i) { rowptr[i] = run; run += cnt[i]; }
    if (tid == 1023) rowptr[NN] = run;
}

__global__ void copy_cursor(const int* __restrict__ rowptr, int* __restrict__ cur) {
    int i = blockIdx.x * 256 + threadIdx.x;
    if (i < NN) cur[i] = rowptr[i];
}

__global__ void scatter_edges(const int* __restrict__ ei, int* __restrict__ cur,
                              int* __restrict__ csr_src) {
    int i = blockIdx.x * 256 + threadIdx.x;
    if (i >= ETOT) return;
    int src = (i < EE) ? ei[i] : (i - EE);
    int dst = (i < EE) ? ei[EE + i] : (i - EE);
    int pos = atomicAdd(&cur[dst], 1);
    csr_src[pos] = src;
}

// ---------------- dtype conversions ----------------
__global__ void f32_to_f16_vec(const float* __restrict__ in, __half* __restrict__ out,
                               int n4) {
    int i = blockIdx.x * 256 + threadIdx.x;
    if (i >= n4) return;
    float4 v = *(const float4*)&in[(size_t)i * 4];
    __half h[4] = {__float2half(v.x), __float2half(v.y), __float2half(v.z), __float2half(v.w)};
    *(uint2*)&out[(size_t)i * 4] = *(uint2*)h;
}

// W[K,256] f32 -> Wt[256][K] fp16
__global__ void w_transpose_f16(const float* __restrict__ W, __half* __restrict__ Wt,
                                int K) {
    int idx = blockIdx.x * 256 + threadIdx.x;
    if (idx >= K * HC) return;
    int n = idx / K, k = idx - n * K;
    Wt[idx] = __float2half(W[(size_t)k * HC + n]);
}

// ---- f16 MFMA GEMM: C[M,256] = A16[M,K] @ Bt16[256,K]^T; writes f32 + fp16 ----
__global__ __launch_bounds__(256) void gemm_f16(const __half* __restrict__ A16,
                                                const __half* __restrict__ Bt16,
                                                float* __restrict__ C,
                                                __half* __restrict__ C16,
                                                int M, int K) {
    __shared__ char lds[32768];           // As 16KB | Bs 16KB, both [128][64] fp16 swizzled
    const int tid  = threadIdx.x;
    const int m0   = blockIdx.y * 128;
    const int n0   = blockIdx.x * 128;
    const int wid  = tid >> 6, lane = tid & 63;
    const int wr   = wid >> 1, wc = wid & 1;
    const int l15  = lane & 15, l4 = lane >> 4;
    const int trow = tid >> 3;            // 0..31
    const int tcol = (tid & 7) * 8;       // fp16 units within 64-wide k slice

    f32x4 acc[4][4] = {};

    for (int k0 = 0; k0 < K; k0 += 64) {
        __syncthreads();
#pragma unroll
        for (int it = 0; it < 4; ++it) {
            int row = trow + it * 32;
            uint4 v = make_uint4(0u, 0u, 0u, 0u);
            int gr = m0 + row;
            if (gr < M) v = *(const uint4*)&A16[(size_t)gr * K + k0 + tcol];
            int off = (row * 128 + tcol * 2) ^ ((row & 7) << 4);
            *(uint4*)(lds + off) = v;
            uint4 w = *(const uint4*)&Bt16[(size_t)(n0 + row) * K + k0 + tcol];
            int offb = 16384 + ((row * 128 + tcol * 2) ^ ((row & 7) << 4));
            *(uint4*)(lds + offb) = w;
        }
        __syncthreads();
#pragma unroll
        for (int ks = 0; ks < 2; ++ks) {
            f16x8 af[4], bf[4];
#pragma unroll
            for (int i = 0; i < 4; ++i) {
                int rowA = wr * 64 + i * 16 + l15;
                int offA = (rowA * 128 + ks * 64 + l4 * 16) ^ ((rowA & 7) << 4);
                af[i] = *(const f16x8*)(lds + offA);
                int rowB = wc * 64 + i * 16 + l15;
                int offB = 16384 + ((rowB * 128 + ks * 64 + l4 * 16) ^ ((rowB & 7) << 4));
                bf[i] = *(const f16x8*)(lds + offB);
            }
#pragma unroll
            for (int i = 0; i < 4; ++i)
#pragma unroll
                for (int j = 0; j < 4; ++j)
                    acc[i][j] = __builtin_amdgcn_mfma_f32_16x16x32_f16(af[i], bf[j], acc[i][j], 0, 0, 0);
        }
    }
    // epilogue: C/D mapping col=lane&15, row=(lane>>4)*4+reg
#pragma unroll
    for (int i = 0; i < 4; ++i) {
#pragma unroll
        for (int r = 0; r < 4; ++r) {
            int row = m0 + wr * 64 + i * 16 + l4 * 4 + r;
            if (row < M) {
#pragma unroll
                for (int j = 0; j < 4; ++j) {
                    int col = n0 + wc * 64 + j * 16 + l15;
                    float v = acc[i][j][r];
                    C[(size_t)row * HC + col]   = v;
                    C16[(size_t)row * HC + col] = __float2half(v);
                }
            }
        }
    }
}

// ---------------- per-node attention scores ----------------
__global__ __launch_bounds__(256) void attn_scores(const float* __restrict__ h,
                                                   const float* __restrict__ a_src,
                                                   const float* __restrict__ a_dst,
                                                   float* __restrict__ es,
                                                   float* __restrict__ ed) {
    int node = blockIdx.x * 4 + (threadIdx.x >> 6);
    int lane = threadIdx.x & 63;
    if (node >= NN) return;
#pragma unroll
    for (int hh = 0; hh < NH; ++hh) {
        float v  = h[(size_t)node * HC + hh * CH + lane];
        float ps = v * a_src[hh * CH + lane];
        float pd = v * a_dst[hh * CH + lane];
#pragma unroll
        for (int off = 32; off > 0; off >>= 1) {
            ps += __shfl_xor(ps, off);
            pd += __shfl_xor(pd, off);
        }
        if (lane == 0) {
            es[node * NH + hh] = ps;
            ed[node * NH + hh] = pd;
        }
    }
}

// ---- softmax: wave per node, butterfly reduce, edge-strided alpha write ----
__global__ __launch_bounds__(256) void softmax_alpha(const float* __restrict__ es,
                                                     const float* __restrict__ ed,
                                                     const int* __restrict__ rowptr,
                                                     const int* __restrict__ csr_src,
                                                     float* __restrict__ alpha) {
    const int node = blockIdx.x * 4 + (threadIdx.x >> 6);
    const int lane = threadIdx.x & 63;
    if (node >= NN) return;
    const int start = rowptr[node];
    const int deg   = rowptr[node + 1] - start;

    float4 ed4 = *(const float4*)&ed[node * NH];
    float edn[NH] = {ed4.x, ed4.y, ed4.z, ed4.w};

    float m[NH], s[NH];
#pragma unroll
    for (int h = 0; h < NH; ++h) { m[h] = -1e30f; s[h] = 0.f; }

    for (int j = lane; j < deg; j += 64) {
        int src = csr_src[start + j];
        float4 e4 = *(const float4*)&es[src * NH];
        float ev[NH] = {e4.x, e4.y, e4.z, e4.w};
#pragma unroll
        for (int h = 0; h < NH; ++h) {
            float e = ev[h] + edn[h];
            e = (e > 0.f) ? e : NEG_SLOPE * e;
            sm_combine(m[h], s[h], e, 1.0f);
        }
    }
#pragma unroll
    for (int h = 0; h < NH; ++h)
#pragma unroll
        for (int off = 32; off > 0; off >>= 1) {
            float om = __shfl_xor(m[h], off);
            float os = __shfl_xor(s[h], off);
            sm_combine(m[h], s[h], om, os);
        }
    float is[NH];
#pragma unroll
    for (int h = 0; h < NH; ++h) is[h] = 1.0f / s[h];

    for (int j = lane; j < deg; j += 64) {
        int src = csr_src[start + j];
        float4 e4 = *(const float4*)&es[src * NH];
        float ev[NH] = {e4.x, e4.y, e4.z, e4.w};
        float4 av;
        float* ap = &av.x;
#pragma unroll
        for (int h = 0; h < NH; ++h) {
            float e = ev[h] + edn[h];
            e = (e > 0.f) ? e : NEG_SLOPE * e;
            ap[h] = __expf(e - m[h]) * is[h];
        }
        *(float4*)&alpha[(size_t)(start + j) * NH] = av;
    }
}

// ------- gather: one wave per node, fp16 features, 4 ch per lane -------
__global__ __launch_bounds__(256) void gat_gather(const __half* __restrict__ hfeat,
                                                  const float* __restrict__ alpha,
                                                  const int* __restrict__ rowptr,
                                                  const int* __restrict__ csr_src,
                                                  const float* __restrict__ bias,
                                                  float* __restrict__ out,
                                                  __half* __restrict__ out16) {
    const int node = blockIdx.x * 4 + (threadIdx.x >> 6);
    const int lane = threadIdx.x & 63;
    if (node >= NN) return;
    const int start = rowptr[node];
    const int deg   = rowptr[node + 1] - start;
    const int hsel  = lane >> 4;   // head for this lane's 4 channels

    float4 acc = make_float4(0.f, 0.f, 0.f, 0.f);
    int j = 0;
    for (; j + 1 < deg; j += 2) {
        int s0 = csr_src[start + j];
        int s1 = csr_src[start + j + 1];
        float a0 = alpha[(size_t)(start + j) * NH + hsel];
        float a1 = alpha[(size_t)(start + j + 1) * NH + hsel];
        uint2 r0 = *(const uint2*)&hfeat[(size_t)s0 * HC + lane * 4];
        uint2 r1 = *(const uint2*)&hfeat[(size_t)s1 * HC + lane * 4];
        float2 f0a = __half22float2(*reinterpret_cast<__half2*>(&r0.x));
        float2 f0b = __half22float2(*reinterpret_cast<__half2*>(&r0.y));
        float2 f1a = __half22float2(*reinterpret_cast<__half2*>(&r1.x));
        float2 f1b = __half22float2(*reinterpret_cast<__half2*>(&r1.y));
        acc.x = fmaf(a0, f0a.x, acc.x);
        acc.y = fmaf(a0, f0a.y, acc.y);
        acc.z = fmaf(a0, f0b.x, acc.z);
        acc.w = fmaf(a0, f0b.y, acc.w);
        acc.x = fmaf(a1, f1a.x, acc.x);
        acc.y = fmaf(a1, f1a.y, acc.y);
        acc.z = fmaf(a1, f1b.x, acc.z);
        acc.w = fmaf(a1, f1b.y, acc.w);
    }
    if (j < deg) {
        int s0 = csr_src[start + j];
        float a0 = alpha[(size_t)(start + j) * NH + hsel];
        uint2 r0 = *(const uint2*)&hfeat[(size_t)s0 * HC + lane * 4];
        float2 f0a = __half22float2(*reinterpret_cast<__half2*>(&r0.x));
        float2 f0b = __half22float2(*reinterpret_cast<__half2*>(&r0.y));
        acc.x = fmaf(a0, f0a.x, acc.x);
        acc.y = fmaf(a0, f0a.y, acc.y);
        acc.z = fmaf(a0, f0b.x, acc.z);
        acc.w = fmaf(a0, f0b.y, acc.w);
    }
    float4 b4 = *(const float4*)&bias[lane * 4];
    float4 o;
    o.x = fmaxf(acc.x + b4.x, 0.f);
    o.y = fmaxf(acc.y + b4.y, 0.f);
    o.z = fmaxf(acc.z + b4.z, 0.f);
    o.w = fmaxf(acc.w + b4.w, 0.f);
    *(float4*)&out[(size_t)node * HC + lane * 4] = o;
    __half h[4] = {__float2half(o.x), __float2half(o.y), __float2half(o.z), __float2half(o.w)};
    *(uint2*)&out16[(size_t)node * HC + lane * 4] = *(uint2*)h;
}

// ---------------- mean pool + final linear ----------------
__global__ __launch_bounds__(256) void pool_sum(const float* __restrict__ h,
                                                const int* __restrict__ batch,
                                                float* __restrict__ sums) {
    int t  = threadIdx.x;
    int n0 = blockIdx.x * 128;
    if (n0 >= NN) return;
    int cur = batch[n0];
    float acc = 0.f;
    int nend = min(n0 + 128, NN);
    for (int n = n0; n < nend; ++n) {
        int g = batch[n];
        if (g != cur) {
            atomicAdd(&sums[cur * HC + t], acc);
            acc = 0.f; cur = g;
        }
        acc += h[(size_t)n * HC + t];
    }
    atomicAdd(&sums[cur * HC + t], acc);
}

// ---- group bounds from sorted batch: no atomics ----
__global__ void batch_bounds(const int* __restrict__ batch,
                             int* __restrict__ beg, int* __restrict__ end) {
    int i = blockIdx.x * 256 + threadIdx.x;
    if (i >= NN) return;
    int g = batch[i];
    if (i == 0      || batch[i - 1] != g) beg[g] = i;
    if (i == NN - 1 || batch[i + 1] != g) end[g] = i + 1;
}

__global__ __launch_bounds__(256) void final_linear(const float* __restrict__ sums,
                                                    const int* __restrict__ beg,
                                                    const int* __restrict__ end,
                                                    const float* __restrict__ Wlin,
                                                    const float* __restrict__ blin,
                                                    float* __restrict__ out) {
    int idx = blockIdx.x * 256 + threadIdx.x;   // 0..1023
    if (idx >= NG * NOUT) return;
    int g = idx >> 4, o = idx & 15;
    float cnt = (float)(end[g] - beg[g]);
    float invc = 1.f / fmaxf(cnt, 1.f);
    float acc = 0.f;
    for (int k = 0; k < HC; ++k) acc += sums[g * HC + k] * Wlin[k * NOUT + o];
    out[idx] = acc * invc + blin[o];
}

// ---------------- launch ----------------
extern "C" void kernel_launch(void* const* d_in, const int* in_sizes, int n_in,
                              void* d_out, int out_size, void* d_ws, size_t ws_size,
                              hipStream_t stream) {
    const float* x      = (const float*)d_in[0];
    const int*   ei     = (const int*)d_in[1];
    const int*   batch  = (const int*)d_in[2];
    const float* W1     = (const float*)d_in[3];
    const float* a_src1 = (const float*)d_in[4];
    const float* a_dst1 = (const float*)d_in[5];
    const float* b1     = (const float*)d_in[6];
    const float* W2     = (const float*)d_in[7];
    const float* a_src2 = (const float*)d_in[8];
    const float* a_dst2 = (const float*)d_in[9];
    const float* b2     = (const float*)d_in[10];
    const float* Wlin   = (const float*)d_in[11];
    const float* blin   = (const float*)d_in[12];
    float* out = (float*)d_out;

    char* p = (char*)d_ws;
    auto take = [&](size_t bytes) {
        char* r = p;
        p += (bytes + 255) & ~(size_t)255;
        return r;
    };
    float*  bufT   = (float*)take((size_t)NN * HC * 4);
    float*  bufH   = (float*)take((size_t)NN * HC * 4);
    __half* bufT16 = (__half*)take((size_t)NN * HC * 2);
    __half* bufH16 = (__half*)take((size_t)NN * HC * 2);
    __half* x16    = (__half*)take((size_t)NN * FIN * 2);
    __half* w1t    = (__half*)take((size_t)FIN * HC * 2);
    __half* w2t    = (__half*)take((size_t)HC * HC * 2);
    float*  es     = (float*)take((size_t)NN * NH * 4);
    float*  ed     = (float*)take((size_t)NN * NH * 4);
    int*    cnt_n  = (int*)take((size_t)NN * 4);
    int*    rowptr = (int*)take((size_t)(NN + 1) * 4);
    int*    cursor = (int*)take((size_t)NN * 4);
    int*    csr    = (int*)take((size_t)ETOT * 4);
    float*  albuf  = (float*)take((size_t)ETOT * NH * 4);
    float*  sums   = (float*)take((size_t)NG * HC * 4);
    int*    gbeg   = (int*)take((size_t)NG * 4);
    int*    gend   = (int*)take((size_t)NG * 4);

    hipMemsetAsync(cnt_n, 0, (size_t)NN * 4, stream);
    hipMemsetAsync(sums, 0, (size_t)NG * HC * 4, stream);
    hipMemsetAsync(gbeg, 0, (size_t)NG * 4, stream);
    hipMemsetAsync(gend, 0, (size_t)NG * 4, stream);

    // CSR + conversions
    count_dst<<<(ETOT + 255) / 256, 256, 0, stream>>>(ei, cnt_n);
    scan_kernel<<<1, 1024, 0, stream>>>(cnt_n, rowptr);
    copy_cursor<<<(NN + 255) / 256, 256, 0, stream>>>(rowptr, cursor);
    scatter_edges<<<(ETOT + 255) / 256, 256, 0, stream>>>(ei, cursor, csr);
    f32_to_f16_vec<<<(NN * FIN / 4 + 255) / 256, 256, 0, stream>>>(x, x16, NN * FIN / 4);
    w_transpose_f16<<<(FIN * HC + 255) / 256, 256, 0, stream>>>(W1, w1t, FIN);
    w_transpose_f16<<<(HC * HC + 255) / 256, 256, 0, stream>>>(W2, w2t, HC);

    // layer 1
    gemm_f16<<<dim3(2, (NN + 127) / 128), 256, 0, stream>>>(x16, w1t, bufT, bufT16, NN, FIN);
    attn_scores<<<(NN + 3) / 4, 256, 0, stream>>>(bufT, a_src1, a_dst1, es, ed);
    softmax_alpha<<<(NN + 3) / 4, 256, 0, stream>>>(es, ed, rowptr, csr, albuf);
    gat_gather<<<(NN + 3) / 4, 256, 0, stream>>>(bufT16, albuf, rowptr, csr, b1, bufH, bufH16);

    // layer 2
    gemm_f16<<<dim3(2, (NN + 127) / 128), 256, 0, stream>>>(bufH16, w2t, bufT, bufT16, NN, HC);
    attn_scores<<<(NN + 3) / 4, 256, 0, stream>>>(bufT, a_src2, a_dst2, es, ed);
    softmax_alpha<<<(NN + 3) / 4, 256, 0, stream>>>(es, ed, rowptr, csr, albuf);
    gat_gather<<<(NN + 3) / 4, 256, 0, stream>>>(bufT16, albuf, rowptr, csr, b2, bufH, bufH16);

    // pool + head
    pool_sum<<<(NN + 127) / 128, 256, 0, stream>>>(bufH, batch, sums);
    batch_bounds<<<(NN + 255) / 256, 256, 0, stream>>>(batch, gbeg, gend);
    final_linear<<<4, 256, 0, stream>>>(sums, gbeg, gend, Wlin, blin, out);
}

// Round 6
// 490.008 us; speedup vs baseline: 2.3609x; 1.1324x over previous
//
#include <hip/hip_runtime.h>
#include <hip/hip_fp16.h>

#define NN   50000
#define EE   800000
#define ETOT 850000   // EE + NN self loops
#define FIN  128
#define HC   256      // H*C
#define NH   4
#define CH   64
#define NG   64
#define NOUT 16
#define NEG_SLOPE 0.2f
#define NBLK 196      // ceil(NN/256)

typedef _Float16 f16x8 __attribute__((ext_vector_type(8)));
typedef float    f32x4 __attribute__((ext_vector_type(4)));

// ---------------- online softmax combine (sentinel -1e30 avoids NaN) ----------
__device__ __forceinline__ void sm_combine(float& m, float& s, float om, float os) {
    float M = fmaxf(m, om);
    s = s * __expf(m - M) + os * __expf(om - M);
    m = M;
}

// ---------------- CSR build ----------------
__global__ void count_dst(const int* __restrict__ ei, int* __restrict__ cnt) {
    int i = blockIdx.x * 256 + threadIdx.x;
    if (i >= ETOT) return;
    int dst = (i < EE) ? ei[EE + i] : (i - EE);
    atomicAdd(&cnt[dst], 1);
}

// ---- 3-phase hierarchical scan (coalesced, multi-block) ----
__global__ __launch_bounds__(256) void scan_local(const int* __restrict__ cnt,
                                                  int* __restrict__ rowptr,
                                                  int* __restrict__ bsum) {
    __shared__ int lds[256];
    const int b = blockIdx.x, tid = threadIdx.x;
    const int i = b * 256 + tid;
    int v = (i < NN) ? cnt[i] : 0;
    lds[tid] = v;
    __syncthreads();
    for (int off = 1; off < 256; off <<= 1) {
        int t = (tid >= off) ? lds[tid - off] : 0;
        __syncthreads();
        lds[tid] += t;
        __syncthreads();
    }
    if (i < NN) rowptr[i] = lds[tid] - v;      // local exclusive prefix
    if (tid == 255) bsum[b] = lds[255];
}

__global__ __launch_bounds__(256) void scan_bsums(const int* __restrict__ bsum,
                                                  int* __restrict__ boff,
                                                  int* __restrict__ rowptr) {
    __shared__ int lds[256];
    const int tid = threadIdx.x;
    int v = (tid < NBLK) ? bsum[tid] : 0;
    lds[tid] = v;
    __syncthreads();
    for (int off = 1; off < 256; off <<= 1) {
        int t = (tid >= off) ? lds[tid - off] : 0;
        __syncthreads();
        lds[tid] += t;
        __syncthreads();
    }
    if (tid < NBLK) boff[tid] = lds[tid] - v;  // exclusive block offset
    if (tid == 255) rowptr[NN] = lds[255];     // total
}

__global__ __launch_bounds__(256) void scan_apply(int* __restrict__ rowptr,
                                                  const int* __restrict__ boff,
                                                  int* __restrict__ cursor) {
    int i = blockIdx.x * 256 + threadIdx.x;
    if (i >= NN) return;
    int r = rowptr[i] + boff[blockIdx.x];
    rowptr[i] = r;
    cursor[i] = r;
}

__global__ void scatter_edges(const int* __restrict__ ei, int* __restrict__ cur,
                              int* __restrict__ csr_src) {
    int i = blockIdx.x * 256 + threadIdx.x;
    if (i >= ETOT) return;
    int src = (i < EE) ? ei[i] : (i - EE);
    int dst = (i < EE) ? ei[EE + i] : (i - EE);
    int pos = atomicAdd(&cur[dst], 1);
    csr_src[pos] = src;
}

// ---------------- dtype conversions ----------------
__global__ void f32_to_f16_vec(const float* __restrict__ in, __half* __restrict__ out,
                               int n4) {
    int i = blockIdx.x * 256 + threadIdx.x;
    if (i >= n4) return;
    float4 v = *(const float4*)&in[(size_t)i * 4];
    __half h[4] = {__float2half(v.x), __float2half(v.y), __float2half(v.z), __float2half(v.w)};
    *(uint2*)&out[(size_t)i * 4] = *(uint2*)h;
}

// W[K,256] f32 -> Wt[256][K] fp16
__global__ void w_transpose_f16(const float* __restrict__ W, __half* __restrict__ Wt,
                                int K) {
    int idx = blockIdx.x * 256 + threadIdx.x;
    if (idx >= K * HC) return;
    int n = idx / K, k = idx - n * K;
    Wt[idx] = __float2half(W[(size_t)k * HC + n]);
}

// ---- f16 MFMA GEMM: C[M,256] = A16[M,K] @ Bt16[256,K]^T; writes f32 + fp16 ----
__global__ __launch_bounds__(256) void gemm_f16(const __half* __restrict__ A16,
                                                const __half* __restrict__ Bt16,
                                                float* __restrict__ C,
                                                __half* __restrict__ C16,
                                                int M, int K) {
    __shared__ char lds[32768];           // As 16KB | Bs 16KB, both [128][64] fp16 swizzled
    const int tid  = threadIdx.x;
    const int m0   = blockIdx.y * 128;
    const int n0   = blockIdx.x * 128;
    const int wid  = tid >> 6, lane = tid & 63;
    const int wr   = wid >> 1, wc = wid & 1;
    const int l15  = lane & 15, l4 = lane >> 4;
    const int trow = tid >> 3;            // 0..31
    const int tcol = (tid & 7) * 8;       // fp16 units within 64-wide k slice

    f32x4 acc[4][4] = {};

    for (int k0 = 0; k0 < K; k0 += 64) {
        __syncthreads();
#pragma unroll
        for (int it = 0; it < 4; ++it) {
            int row = trow + it * 32;
            uint4 v = make_uint4(0u, 0u, 0u, 0u);
            int gr = m0 + row;
            if (gr < M) v = *(const uint4*)&A16[(size_t)gr * K + k0 + tcol];
            int off = (row * 128 + tcol * 2) ^ ((row & 7) << 4);
            *(uint4*)(lds + off) = v;
            uint4 w = *(const uint4*)&Bt16[(size_t)(n0 + row) * K + k0 + tcol];
            int offb = 16384 + ((row * 128 + tcol * 2) ^ ((row & 7) << 4));
            *(uint4*)(lds + offb) = w;
        }
        __syncthreads();
#pragma unroll
        for (int ks = 0; ks < 2; ++ks) {
            f16x8 af[4], bf[4];
#pragma unroll
            for (int i = 0; i < 4; ++i) {
                int rowA = wr * 64 + i * 16 + l15;
                int offA = (rowA * 128 + ks * 64 + l4 * 16) ^ ((rowA & 7) << 4);
                af[i] = *(const f16x8*)(lds + offA);
                int rowB = wc * 64 + i * 16 + l15;
                int offB = 16384 + ((rowB * 128 + ks * 64 + l4 * 16) ^ ((rowB & 7) << 4));
                bf[i] = *(const f16x8*)(lds + offB);
            }
#pragma unroll
            for (int i = 0; i < 4; ++i)
#pragma unroll
                for (int j = 0; j < 4; ++j)
                    acc[i][j] = __builtin_amdgcn_mfma_f32_16x16x32_f16(af[i], bf[j], acc[i][j], 0, 0, 0);
        }
    }
    // epilogue: C/D mapping col=lane&15, row=(lane>>4)*4+reg
#pragma unroll
    for (int i = 0; i < 4; ++i) {
#pragma unroll
        for (int r = 0; r < 4; ++r) {
            int row = m0 + wr * 64 + i * 16 + l4 * 4 + r;
            if (row < M) {
#pragma unroll
                for (int j = 0; j < 4; ++j) {
                    int col = n0 + wc * 64 + j * 16 + l15;
                    float v = acc[i][j][r];
                    C[(size_t)row * HC + col]   = v;
                    C16[(size_t)row * HC + col] = __float2half(v);
                }
            }
        }
    }
}

// ---------------- per-node attention scores ----------------
__global__ __launch_bounds__(256) void attn_scores(const float* __restrict__ h,
                                                   const float* __restrict__ a_src,
                                                   const float* __restrict__ a_dst,
                                                   float* __restrict__ es,
                                                   float* __restrict__ ed) {
    int node = blockIdx.x * 4 + (threadIdx.x >> 6);
    int lane = threadIdx.x & 63;
    if (node >= NN) return;
#pragma unroll
    for (int hh = 0; hh < NH; ++hh) {
        float v  = h[(size_t)node * HC + hh * CH + lane];
        float ps = v * a_src[hh * CH + lane];
        float pd = v * a_dst[hh * CH + lane];
#pragma unroll
        for (int off = 32; off > 0; off >>= 1) {
            ps += __shfl_xor(ps, off);
            pd += __shfl_xor(pd, off);
        }
        if (lane == 0) {
            es[node * NH + hh] = ps;
            ed[node * NH + hh] = pd;
        }
    }
}

// ---- softmax: wave per node, butterfly reduce, edge-strided alpha write ----
__global__ __launch_bounds__(256) void softmax_alpha(const float* __restrict__ es,
                                                     const float* __restrict__ ed,
                                                     const int* __restrict__ rowptr,
                                                     const int* __restrict__ csr_src,
                                                     float* __restrict__ alpha) {
    const int node = blockIdx.x * 4 + (threadIdx.x >> 6);
    const int lane = threadIdx.x & 63;
    if (node >= NN) return;
    const int start = rowptr[node];
    const int deg   = rowptr[node + 1] - start;

    float4 ed4 = *(const float4*)&ed[node * NH];
    float edn[NH] = {ed4.x, ed4.y, ed4.z, ed4.w};

    float m[NH], s[NH];
#pragma unroll
    for (int h = 0; h < NH; ++h) { m[h] = -1e30f; s[h] = 0.f; }

    for (int j = lane; j < deg; j += 64) {
        int src = csr_src[start + j];
        float4 e4 = *(const float4*)&es[src * NH];
        float ev[NH] = {e4.x, e4.y, e4.z, e4.w};
#pragma unroll
        for (int h = 0; h < NH; ++h) {
            float e = ev[h] + edn[h];
            e = (e > 0.f) ? e : NEG_SLOPE * e;
            sm_combine(m[h], s[h], e, 1.0f);
        }
    }
#pragma unroll
    for (int h = 0; h < NH; ++h)
#pragma unroll
        for (int off = 32; off > 0; off >>= 1) {
            float om = __shfl_xor(m[h], off);
            float os = __shfl_xor(s[h], off);
            sm_combine(m[h], s[h], om, os);
        }
    float is[NH];
#pragma unroll
    for (int h = 0; h < NH; ++h) is[h] = 1.0f / s[h];

    for (int j = lane; j < deg; j += 64) {
        int src = csr_src[start + j];
        float4 e4 = *(const float4*)&es[src * NH];
        float ev[NH] = {e4.x, e4.y, e4.z, e4.w};
        float4 av;
        float* ap = &av.x;
#pragma unroll
        for (int h = 0; h < NH; ++h) {
            float e = ev[h] + edn[h];
            e = (e > 0.f) ? e : NEG_SLOPE * e;
            ap[h] = __expf(e - m[h]) * is[h];
        }
        *(float4*)&alpha[(size_t)(start + j) * NH] = av;
    }
}

// ------- gather: one wave per node, fp16 features, 4 ch per lane -------
__global__ __launch_bounds__(256) void gat_gather(const __half* __restrict__ hfeat,
                                                  const float* __restrict__ alpha,
                                                  const int* __restrict__ rowptr,
                                                  const int* __restrict__ csr_src,
                                                  const float* __restrict__ bias,
                                                  float* __restrict__ out,
                                                  __half* __restrict__ out16) {
    const int node = blockIdx.x * 4 + (threadIdx.x >> 6);
    const int lane = threadIdx.x & 63;
    if (node >= NN) return;
    const int start = rowptr[node];
    const int deg   = rowptr[node + 1] - start;
    const int hsel  = lane >> 4;   // head for this lane's 4 channels

    float4 acc = make_float4(0.f, 0.f, 0.f, 0.f);
    int j = 0;
    for (; j + 1 < deg; j += 2) {
        int s0 = csr_src[start + j];
        int s1 = csr_src[start + j + 1];
        float a0 = alpha[(size_t)(start + j) * NH + hsel];
        float a1 = alpha[(size_t)(start + j + 1) * NH + hsel];
        uint2 r0 = *(const uint2*)&hfeat[(size_t)s0 * HC + lane * 4];
        uint2 r1 = *(const uint2*)&hfeat[(size_t)s1 * HC + lane * 4];
        float2 f0a = __half22float2(*reinterpret_cast<__half2*>(&r0.x));
        float2 f0b = __half22float2(*reinterpret_cast<__half2*>(&r0.y));
        float2 f1a = __half22float2(*reinterpret_cast<__half2*>(&r1.x));
        float2 f1b = __half22float2(*reinterpret_cast<__half2*>(&r1.y));
        acc.x = fmaf(a0, f0a.x, acc.x);
        acc.y = fmaf(a0, f0a.y, acc.y);
        acc.z = fmaf(a0, f0b.x, acc.z);
        acc.w = fmaf(a0, f0b.y, acc.w);
        acc.x = fmaf(a1, f1a.x, acc.x);
        acc.y = fmaf(a1, f1a.y, acc.y);
        acc.z = fmaf(a1, f1b.x, acc.z);
        acc.w = fmaf(a1, f1b.y, acc.w);
    }
    if (j < deg) {
        int s0 = csr_src[start + j];
        float a0 = alpha[(size_t)(start + j) * NH + hsel];
        uint2 r0 = *(const uint2*)&hfeat[(size_t)s0 * HC + lane * 4];
        float2 f0a = __half22float2(*reinterpret_cast<__half2*>(&r0.x));
        float2 f0b = __half22float2(*reinterpret_cast<__half2*>(&r0.y));
        acc.x = fmaf(a0, f0a.x, acc.x);
        acc.y = fmaf(a0, f0a.y, acc.y);
        acc.z = fmaf(a0, f0b.x, acc.z);
        acc.w = fmaf(a0, f0b.y, acc.w);
    }
    float4 b4 = *(const float4*)&bias[lane * 4];
    float4 o;
    o.x = fmaxf(acc.x + b4.x, 0.f);
    o.y = fmaxf(acc.y + b4.y, 0.f);
    o.z = fmaxf(acc.z + b4.z, 0.f);
    o.w = fmaxf(acc.w + b4.w, 0.f);
    *(float4*)&out[(size_t)node * HC + lane * 4] = o;
    __half h[4] = {__float2half(o.x), __float2half(o.y), __float2half(o.z), __float2half(o.w)};
    *(uint2*)&out16[(size_t)node * HC + lane * 4] = *(uint2*)h;
}

// ---------------- mean pool + final linear ----------------
__global__ __launch_bounds__(256) void pool_sum(const float* __restrict__ h,
                                                const int* __restrict__ batch,
                                                float* __restrict__ sums) {
    int t  = threadIdx.x;
    int n0 = blockIdx.x * 128;
    if (n0 >= NN) return;
    int cur = batch[n0];
    float acc = 0.f;
    int nend = min(n0 + 128, NN);
    for (int n = n0; n < nend; ++n) {
        int g = batch[n];
        if (g != cur) {
            atomicAdd(&sums[cur * HC + t], acc);
            acc = 0.f; cur = g;
        }
        acc += h[(size_t)n * HC + t];
    }
    atomicAdd(&sums[cur * HC + t], acc);
}

// ---- group bounds from sorted batch: no atomics ----
__global__ void batch_bounds(const int* __restrict__ batch,
                             int* __restrict__ beg, int* __restrict__ end) {
    int i = blockIdx.x * 256 + threadIdx.x;
    if (i >= NN) return;
    int g = batch[i];
    if (i == 0      || batch[i - 1] != g) beg[g] = i;
    if (i == NN - 1 || batch[i + 1] != g) end[g] = i + 1;
}

__global__ __launch_bounds__(256) void final_linear(const float* __restrict__ sums,
                                                    const int* __restrict__ beg,
                                                    const int* __restrict__ end,
                                                    const float* __restrict__ Wlin,
                                                    const float* __restrict__ blin,
                                                    float* __restrict__ out) {
    int idx = blockIdx.x * 256 + threadIdx.x;   // 0..1023
    if (idx >= NG * NOUT) return;
    int g = idx >> 4, o = idx & 15;
    float cnt = (float)(end[g] - beg[g]);
    float invc = 1.f / fmaxf(cnt, 1.f);
    float acc = 0.f;
    for (int k = 0; k < HC; ++k) acc += sums[g * HC + k] * Wlin[k * NOUT + o];
    out[idx] = acc * invc + blin[o];
}

// ---------------- launch ----------------
extern "C" void kernel_launch(void* const* d_in, const int* in_sizes, int n_in,
                              void* d_out, int out_size, void* d_ws, size_t ws_size,
                              hipStream_t stream) {
    const float* x      = (const float*)d_in[0];
    const int*   ei     = (const int*)d_in[1];
    const int*   batch  = (const int*)d_in[2];
    const float* W1     = (const float*)d_in[3];
    const float* a_src1 = (const float*)d_in[4];
    const float* a_dst1 = (const float*)d_in[5];
    const float* b1     = (const float*)d_in[6];
    const float* W2     = (const float*)d_in[7];
    const float* a_src2 = (const float*)d_in[8];
    const float* a_dst2 = (const float*)d_in[9];
    const float* b2     = (const float*)d_in[10];
    const float* Wlin   = (const float*)d_in[11];
    const float* blin   = (const float*)d_in[12];
    float* out = (float*)d_out;

    char* p = (char*)d_ws;
    auto take = [&](size_t bytes) {
        char* r = p;
        p += (bytes + 255) & ~(size_t)255;
        return r;
    };
    float*  bufT   = (float*)take((size_t)NN * HC * 4);
    float*  bufH   = (float*)take((size_t)NN * HC * 4);
    __half* bufT16 = (__half*)take((size_t)NN * HC * 2);
    __half* bufH16 = (__half*)take((size_t)NN * HC * 2);
    __half* x16    = (__half*)take((size_t)NN * FIN * 2);
    __half* w1t    = (__half*)take((size_t)FIN * HC * 2);
    __half* w2t    = (__half*)take((size_t)HC * HC * 2);
    float*  es     = (float*)take((size_t)NN * NH * 4);
    float*  ed     = (float*)take((size_t)NN * NH * 4);
    int*    cnt_n  = (int*)take((size_t)NN * 4);
    int*    rowptr = (int*)take((size_t)(NN + 1) * 4);
    int*    cursor = (int*)take((size_t)NN * 4);
    int*    csr    = (int*)take((size_t)ETOT * 4);
    int*    bsum   = (int*)take((size_t)NBLK * 4);
    int*    boff   = (int*)take((size_t)NBLK * 4);
    float*  albuf  = (float*)take((size_t)ETOT * NH * 4);
    float*  sums   = (float*)take((size_t)NG * HC * 4);
    int*    gbeg   = (int*)take((size_t)NG * 4);
    int*    gend   = (int*)take((size_t)NG * 4);

    hipMemsetAsync(cnt_n, 0, (size_t)NN * 4, stream);
    hipMemsetAsync(sums, 0, (size_t)NG * HC * 4, stream);
    hipMemsetAsync(gbeg, 0, (size_t)NG * 4, stream);
    hipMemsetAsync(gend, 0, (size_t)NG * 4, stream);

    // CSR + conversions
    count_dst<<<(ETOT + 255) / 256, 256, 0, stream>>>(ei, cnt_n);
    scan_local<<<NBLK, 256, 0, stream>>>(cnt_n, rowptr, bsum);
    scan_bsums<<<1, 256, 0, stream>>>(bsum, boff, rowptr);
    scan_apply<<<NBLK, 256, 0, stream>>>(rowptr, boff, cursor);
    scatter_edges<<<(ETOT + 255) / 256, 256, 0, stream>>>(ei, cursor, csr);
    f32_to_f16_vec<<<(NN * FIN / 4 + 255) / 256, 256, 0, stream>>>(x, x16, NN * FIN / 4);
    w_transpose_f16<<<(FIN * HC + 255) / 256, 256, 0, stream>>>(W1, w1t, FIN);
    w_transpose_f16<<<(HC * HC + 255) / 256, 256, 0, stream>>>(W2, w2t, HC);

    // layer 1
    gemm_f16<<<dim3(2, (NN + 127) / 128), 256, 0, stream>>>(x16, w1t, bufT, bufT16, NN, FIN);
    attn_scores<<<(NN + 3) / 4, 256, 0, stream>>>(bufT, a_src1, a_dst1, es, ed);
    softmax_alpha<<<(NN + 3) / 4, 256, 0, stream>>>(es, ed, rowptr, csr, albuf);
    gat_gather<<<(NN + 3) / 4, 256, 0, stream>>>(bufT16, albuf, rowptr, csr, b1, bufH, bufH16);

    // layer 2
    gemm_f16<<<dim3(2, (NN + 127) / 128), 256, 0, stream>>>(bufH16, w2t, bufT, bufT16, NN, HC);
    attn_scores<<<(NN + 3) / 4, 256, 0, stream>>>(bufT, a_src2, a_dst2, es, ed);
    softmax_alpha<<<(NN + 3) / 4, 256, 0, stream>>>(es, ed, rowptr, csr, albuf);
    gat_gather<<<(NN + 3) / 4, 256, 0, stream>>>(bufT16, albuf, rowptr, csr, b2, bufH, bufH16);

    // pool + head
    pool_sum<<<(NN + 127) / 128, 256, 0, stream>>>(bufH, batch, sums);
    batch_bounds<<<(NN + 255) / 256, 256, 0, stream>>>(batch, gbeg, gend);
    final_linear<<<4, 256, 0, stream>>>(sums, gbeg, gend, Wlin, blin, out);
}

// Round 7
// 448.431 us; speedup vs baseline: 2.5797x; 1.0927x over previous
//
#include <hip/hip_runtime.h>
#include <hip/hip_fp16.h>

#define NN   50000
#define EE   800000
#define ETOT 850000   // EE + NN self loops
#define FIN  128
#define HC   256      // H*C
#define NH   4
#define CH   64
#define NG   64
#define NOUT 16
#define NEG_SLOPE 0.2f
#define NBLK 196      // ceil(NN/256)

typedef _Float16 f16x8 __attribute__((ext_vector_type(8)));
typedef float    f32x4 __attribute__((ext_vector_type(4)));

// ---------------- online softmax combine (sentinel -1e30 avoids NaN) ----------
__device__ __forceinline__ void sm_combine(float& m, float& s, float om, float os) {
    float M = fmaxf(m, om);
    s = s * __expf(m - M) + os * __expf(om - M);
    m = M;
}

// ---------------- CSR build ----------------
__global__ void count_dst(const int* __restrict__ ei, int* __restrict__ cnt) {
    int i = blockIdx.x * 256 + threadIdx.x;
    if (i >= ETOT) return;
    int dst = (i < EE) ? ei[EE + i] : (i - EE);
    atomicAdd(&cnt[dst], 1);
}

// ---- 3-phase hierarchical scan (coalesced, multi-block) ----
__global__ __launch_bounds__(256) void scan_local(const int* __restrict__ cnt,
                                                  int* __restrict__ rowptr,
                                                  int* __restrict__ bsum) {
    __shared__ int lds[256];
    const int b = blockIdx.x, tid = threadIdx.x;
    const int i = b * 256 + tid;
    int v = (i < NN) ? cnt[i] : 0;
    lds[tid] = v;
    __syncthreads();
    for (int off = 1; off < 256; off <<= 1) {
        int t = (tid >= off) ? lds[tid - off] : 0;
        __syncthreads();
        lds[tid] += t;
        __syncthreads();
    }
    if (i < NN) rowptr[i] = lds[tid] - v;      // local exclusive prefix
    if (tid == 255) bsum[b] = lds[255];
}

__global__ __launch_bounds__(256) void scan_bsums(const int* __restrict__ bsum,
                                                  int* __restrict__ boff,
                                                  int* __restrict__ rowptr) {
    __shared__ int lds[256];
    const int tid = threadIdx.x;
    int v = (tid < NBLK) ? bsum[tid] : 0;
    lds[tid] = v;
    __syncthreads();
    for (int off = 1; off < 256; off <<= 1) {
        int t = (tid >= off) ? lds[tid - off] : 0;
        __syncthreads();
        lds[tid] += t;
        __syncthreads();
    }
    if (tid < NBLK) boff[tid] = lds[tid] - v;  // exclusive block offset
    if (tid == 255) rowptr[NN] = lds[255];     // total
}

__global__ __launch_bounds__(256) void scan_apply(int* __restrict__ rowptr,
                                                  const int* __restrict__ boff,
                                                  int* __restrict__ cursor) {
    int i = blockIdx.x * 256 + threadIdx.x;
    if (i >= NN) return;
    int r = rowptr[i] + boff[blockIdx.x];
    rowptr[i] = r;
    cursor[i] = r;
}

__global__ void scatter_edges(const int* __restrict__ ei, int* __restrict__ cur,
                              int* __restrict__ csr_src) {
    int i = blockIdx.x * 256 + threadIdx.x;
    if (i >= ETOT) return;
    int src = (i < EE) ? ei[i] : (i - EE);
    int dst = (i < EE) ? ei[EE + i] : (i - EE);
    int pos = atomicAdd(&cur[dst], 1);
    csr_src[pos] = src;
}

// ---------------- dtype conversions ----------------
__global__ void f32_to_f16_vec(const float* __restrict__ in, __half* __restrict__ out,
                               int n4) {
    int i = blockIdx.x * 256 + threadIdx.x;
    if (i >= n4) return;
    float4 v = *(const float4*)&in[(size_t)i * 4];
    __half h[4] = {__float2half(v.x), __float2half(v.y), __float2half(v.z), __float2half(v.w)};
    *(uint2*)&out[(size_t)i * 4] = *(uint2*)h;
}

// W[K,256] f32 -> Wt[256][K] fp16
__global__ void w_transpose_f16(const float* __restrict__ W, __half* __restrict__ Wt,
                                int K) {
    int idx = blockIdx.x * 256 + threadIdx.x;
    if (idx >= K * HC) return;
    int n = idx / K, k = idx - n * K;
    Wt[idx] = __float2half(W[(size_t)k * HC + n]);
}

// ---- f16 MFMA GEMM: C16[M,256] = A16[M,K] @ Bt16[256,K]^T (fp16 out only) ----
__global__ __launch_bounds__(256) void gemm_f16(const __half* __restrict__ A16,
                                                const __half* __restrict__ Bt16,
                                                __half* __restrict__ C16,
                                                int M, int K) {
    __shared__ char lds[32768];           // As 16KB | Bs 16KB, both [128][64] fp16 swizzled
    const int tid  = threadIdx.x;
    const int m0   = blockIdx.y * 128;
    const int n0   = blockIdx.x * 128;
    const int wid  = tid >> 6, lane = tid & 63;
    const int wr   = wid >> 1, wc = wid & 1;
    const int l15  = lane & 15, l4 = lane >> 4;
    const int trow = tid >> 3;            // 0..31
    const int tcol = (tid & 7) * 8;       // fp16 units within 64-wide k slice

    f32x4 acc[4][4] = {};

    for (int k0 = 0; k0 < K; k0 += 64) {
        __syncthreads();
#pragma unroll
        for (int it = 0; it < 4; ++it) {
            int row = trow + it * 32;
            uint4 v = make_uint4(0u, 0u, 0u, 0u);
            int gr = m0 + row;
            if (gr < M) v = *(const uint4*)&A16[(size_t)gr * K + k0 + tcol];
            int off = (row * 128 + tcol * 2) ^ ((row & 7) << 4);
            *(uint4*)(lds + off) = v;
            uint4 w = *(const uint4*)&Bt16[(size_t)(n0 + row) * K + k0 + tcol];
            int offb = 16384 + ((row * 128 + tcol * 2) ^ ((row & 7) << 4));
            *(uint4*)(lds + offb) = w;
        }
        __syncthreads();
#pragma unroll
        for (int ks = 0; ks < 2; ++ks) {
            f16x8 af[4], bf[4];
#pragma unroll
            for (int i = 0; i < 4; ++i) {
                int rowA = wr * 64 + i * 16 + l15;
                int offA = (rowA * 128 + ks * 64 + l4 * 16) ^ ((rowA & 7) << 4);
                af[i] = *(const f16x8*)(lds + offA);
                int rowB = wc * 64 + i * 16 + l15;
                int offB = 16384 + ((rowB * 128 + ks * 64 + l4 * 16) ^ ((rowB & 7) << 4));
                bf[i] = *(const f16x8*)(lds + offB);
            }
#pragma unroll
            for (int i = 0; i < 4; ++i)
#pragma unroll
                for (int j = 0; j < 4; ++j)
                    acc[i][j] = __builtin_amdgcn_mfma_f32_16x16x32_f16(af[i], bf[j], acc[i][j], 0, 0, 0);
        }
    }
    // epilogue: C/D mapping col=lane&15, row=(lane>>4)*4+reg
#pragma unroll
    for (int i = 0; i < 4; ++i) {
#pragma unroll
        for (int r = 0; r < 4; ++r) {
            int row = m0 + wr * 64 + i * 16 + l4 * 4 + r;
            if (row < M) {
#pragma unroll
                for (int j = 0; j < 4; ++j) {
                    int col = n0 + wc * 64 + j * 16 + l15;
                    C16[(size_t)row * HC + col] = __float2half(acc[i][j][r]);
                }
            }
        }
    }
}

// ---------------- per-node attention scores (fp16 features) ----------------
__global__ __launch_bounds__(256) void attn_scores(const __half* __restrict__ h,
                                                   const float* __restrict__ a_src,
                                                   const float* __restrict__ a_dst,
                                                   float* __restrict__ es,
                                                   float* __restrict__ ed) {
    int node = blockIdx.x * 4 + (threadIdx.x >> 6);
    int lane = threadIdx.x & 63;
    if (node >= NN) return;
#pragma unroll
    for (int hh = 0; hh < NH; ++hh) {
        float v  = __half2float(h[(size_t)node * HC + hh * CH + lane]);
        float ps = v * a_src[hh * CH + lane];
        float pd = v * a_dst[hh * CH + lane];
#pragma unroll
        for (int off = 32; off > 0; off >>= 1) {
            ps += __shfl_xor(ps, off);
            pd += __shfl_xor(pd, off);
        }
        if (lane == 0) {
            es[node * NH + hh] = ps;
            ed[node * NH + hh] = pd;
        }
    }
}

// ---- softmax: wave per node, butterfly reduce, packed-fp16 alpha write ----
__global__ __launch_bounds__(256) void softmax_alpha(const float* __restrict__ es,
                                                     const float* __restrict__ ed,
                                                     const int* __restrict__ rowptr,
                                                     const int* __restrict__ csr_src,
                                                     __half* __restrict__ alpha16) {
    const int node = blockIdx.x * 4 + (threadIdx.x >> 6);
    const int lane = threadIdx.x & 63;
    if (node >= NN) return;
    const int start = rowptr[node];
    const int deg   = rowptr[node + 1] - start;

    float4 ed4 = *(const float4*)&ed[node * NH];
    float edn[NH] = {ed4.x, ed4.y, ed4.z, ed4.w};

    float m[NH], s[NH];
#pragma unroll
    for (int h = 0; h < NH; ++h) { m[h] = -1e30f; s[h] = 0.f; }

    for (int j = lane; j < deg; j += 64) {
        int src = csr_src[start + j];
        float4 e4 = *(const float4*)&es[src * NH];
        float ev[NH] = {e4.x, e4.y, e4.z, e4.w};
#pragma unroll
        for (int h = 0; h < NH; ++h) {
            float e = ev[h] + edn[h];
            e = (e > 0.f) ? e : NEG_SLOPE * e;
            sm_combine(m[h], s[h], e, 1.0f);
        }
    }
#pragma unroll
    for (int h = 0; h < NH; ++h)
#pragma unroll
        for (int off = 32; off > 0; off >>= 1) {
            float om = __shfl_xor(m[h], off);
            float os = __shfl_xor(s[h], off);
            sm_combine(m[h], s[h], om, os);
        }
    float is[NH];
#pragma unroll
    for (int h = 0; h < NH; ++h) is[h] = 1.0f / s[h];

    for (int j = lane; j < deg; j += 64) {
        int src = csr_src[start + j];
        float4 e4 = *(const float4*)&es[src * NH];
        float ev[NH] = {e4.x, e4.y, e4.z, e4.w};
        __half ah[4];
#pragma unroll
        for (int h = 0; h < NH; ++h) {
            float e = ev[h] + edn[h];
            e = (e > 0.f) ? e : NEG_SLOPE * e;
            ah[h] = __float2half(__expf(e - m[h]) * is[h]);
        }
        *(uint2*)&alpha16[(size_t)(start + j) * NH] = *(uint2*)ah;
    }
}

// ------- gather: one wave per node, fp16 features, unroll-4 MLP -------
__global__ __launch_bounds__(256) void gat_gather(const __half* __restrict__ hfeat,
                                                  const __half* __restrict__ alpha16,
                                                  const int* __restrict__ rowptr,
                                                  const int* __restrict__ csr_src,
                                                  const float* __restrict__ bias,
                                                  __half* __restrict__ out16) {
    const int node = blockIdx.x * 4 + (threadIdx.x >> 6);
    const int lane = threadIdx.x & 63;
    if (node >= NN) return;
    const int start = rowptr[node];
    const int deg   = rowptr[node + 1] - start;
    const int hsel  = lane >> 4;   // head for this lane's 4 channels

    float4 acc = make_float4(0.f, 0.f, 0.f, 0.f);
    int j = 0;
    for (; j + 3 < deg; j += 4) {
        const int e = start + j;
        int s0 = csr_src[e + 0];
        int s1 = csr_src[e + 1];
        int s2 = csr_src[e + 2];
        int s3 = csr_src[e + 3];
        float a0 = __half2float(alpha16[(size_t)(e + 0) * NH + hsel]);
        float a1 = __half2float(alpha16[(size_t)(e + 1) * NH + hsel]);
        float a2 = __half2float(alpha16[(size_t)(e + 2) * NH + hsel]);
        float a3 = __half2float(alpha16[(size_t)(e + 3) * NH + hsel]);
        uint2 r0 = *(const uint2*)&hfeat[(size_t)s0 * HC + lane * 4];
        uint2 r1 = *(const uint2*)&hfeat[(size_t)s1 * HC + lane * 4];
        uint2 r2 = *(const uint2*)&hfeat[(size_t)s2 * HC + lane * 4];
        uint2 r3 = *(const uint2*)&hfeat[(size_t)s3 * HC + lane * 4];
        float2 f0a = __half22float2(*reinterpret_cast<__half2*>(&r0.x));
        float2 f0b = __half22float2(*reinterpret_cast<__half2*>(&r0.y));
        float2 f1a = __half22float2(*reinterpret_cast<__half2*>(&r1.x));
        float2 f1b = __half22float2(*reinterpret_cast<__half2*>(&r1.y));
        float2 f2a = __half22float2(*reinterpret_cast<__half2*>(&r2.x));
        float2 f2b = __half22float2(*reinterpret_cast<__half2*>(&r2.y));
        float2 f3a = __half22float2(*reinterpret_cast<__half2*>(&r3.x));
        float2 f3b = __half22float2(*reinterpret_cast<__half2*>(&r3.y));
        acc.x = fmaf(a0, f0a.x, acc.x); acc.y = fmaf(a0, f0a.y, acc.y);
        acc.z = fmaf(a0, f0b.x, acc.z); acc.w = fmaf(a0, f0b.y, acc.w);
        acc.x = fmaf(a1, f1a.x, acc.x); acc.y = fmaf(a1, f1a.y, acc.y);
        acc.z = fmaf(a1, f1b.x, acc.z); acc.w = fmaf(a1, f1b.y, acc.w);
        acc.x = fmaf(a2, f2a.x, acc.x); acc.y = fmaf(a2, f2a.y, acc.y);
        acc.z = fmaf(a2, f2b.x, acc.z); acc.w = fmaf(a2, f2b.y, acc.w);
        acc.x = fmaf(a3, f3a.x, acc.x); acc.y = fmaf(a3, f3a.y, acc.y);
        acc.z = fmaf(a3, f3b.x, acc.z); acc.w = fmaf(a3, f3b.y, acc.w);
    }
    for (; j < deg; ++j) {
        const int e = start + j;
        int s0 = csr_src[e];
        float a0 = __half2float(alpha16[(size_t)e * NH + hsel]);
        uint2 r0 = *(const uint2*)&hfeat[(size_t)s0 * HC + lane * 4];
        float2 f0a = __half22float2(*reinterpret_cast<__half2*>(&r0.x));
        float2 f0b = __half22float2(*reinterpret_cast<__half2*>(&r0.y));
        acc.x = fmaf(a0, f0a.x, acc.x); acc.y = fmaf(a0, f0a.y, acc.y);
        acc.z = fmaf(a0, f0b.x, acc.z); acc.w = fmaf(a0, f0b.y, acc.w);
    }
    float4 b4 = *(const float4*)&bias[lane * 4];
    __half h[4];
    h[0] = __float2half(fmaxf(acc.x + b4.x, 0.f));
    h[1] = __float2half(fmaxf(acc.y + b4.y, 0.f));
    h[2] = __float2half(fmaxf(acc.z + b4.z, 0.f));
    h[3] = __float2half(fmaxf(acc.w + b4.w, 0.f));
    *(uint2*)&out16[(size_t)node * HC + lane * 4] = *(uint2*)h;
}

// ---------------- mean pool + final linear ----------------
__global__ __launch_bounds__(256) void pool_sum(const __half* __restrict__ h,
                                                const int* __restrict__ batch,
                                                float* __restrict__ sums) {
    int t  = threadIdx.x;
    int n0 = blockIdx.x * 128;
    if (n0 >= NN) return;
    int cur = batch[n0];
    float acc = 0.f;
    int nend = min(n0 + 128, NN);
    for (int n = n0; n < nend; ++n) {
        int g = batch[n];
        if (g != cur) {
            atomicAdd(&sums[cur * HC + t], acc);
            acc = 0.f; cur = g;
        }
        acc += __half2float(h[(size_t)n * HC + t]);
    }
    atomicAdd(&sums[cur * HC + t], acc);
}

// ---- group bounds from sorted batch: no atomics ----
__global__ void batch_bounds(const int* __restrict__ batch,
                             int* __restrict__ beg, int* __restrict__ end) {
    int i = blockIdx.x * 256 + threadIdx.x;
    if (i >= NN) return;
    int g = batch[i];
    if (i == 0      || batch[i - 1] != g) beg[g] = i;
    if (i == NN - 1 || batch[i + 1] != g) end[g] = i + 1;
}

__global__ __launch_bounds__(256) void final_linear(const float* __restrict__ sums,
                                                    const int* __restrict__ beg,
                                                    const int* __restrict__ end,
                                                    const float* __restrict__ Wlin,
                                                    const float* __restrict__ blin,
                                                    float* __restrict__ out) {
    int idx = blockIdx.x * 256 + threadIdx.x;   // 0..1023
    if (idx >= NG * NOUT) return;
    int g = idx >> 4, o = idx & 15;
    float cnt = (float)(end[g] - beg[g]);
    float invc = 1.f / fmaxf(cnt, 1.f);
    float acc = 0.f;
    for (int k = 0; k < HC; ++k) acc += sums[g * HC + k] * Wlin[k * NOUT + o];
    out[idx] = acc * invc + blin[o];
}

// ---------------- launch ----------------
extern "C" void kernel_launch(void* const* d_in, const int* in_sizes, int n_in,
                              void* d_out, int out_size, void* d_ws, size_t ws_size,
                              hipStream_t stream) {
    const float* x      = (const float*)d_in[0];
    const int*   ei     = (const int*)d_in[1];
    const int*   batch  = (const int*)d_in[2];
    const float* W1     = (const float*)d_in[3];
    const float* a_src1 = (const float*)d_in[4];
    const float* a_dst1 = (const float*)d_in[5];
    const float* b1     = (const float*)d_in[6];
    const float* W2     = (const float*)d_in[7];
    const float* a_src2 = (const float*)d_in[8];
    const float* a_dst2 = (const float*)d_in[9];
    const float* b2     = (const float*)d_in[10];
    const float* Wlin   = (const float*)d_in[11];
    const float* blin   = (const float*)d_in[12];
    float* out = (float*)d_out;

    char* p = (char*)d_ws;
    auto take = [&](size_t bytes) {
        char* r = p;
        p += (bytes + 255) & ~(size_t)255;
        return r;
    };
    __half* bufT16 = (__half*)take((size_t)NN * HC * 2);
    __half* bufH16 = (__half*)take((size_t)NN * HC * 2);
    __half* x16    = (__half*)take((size_t)NN * FIN * 2);
    __half* w1t    = (__half*)take((size_t)FIN * HC * 2);
    __half* w2t    = (__half*)take((size_t)HC * HC * 2);
    float*  es     = (float*)take((size_t)NN * NH * 4);
    float*  ed     = (float*)take((size_t)NN * NH * 4);
    int*    cnt_n  = (int*)take((size_t)NN * 4);
    int*    rowptr = (int*)take((size_t)(NN + 1) * 4);
    int*    cursor = (int*)take((size_t)NN * 4);
    int*    csr    = (int*)take((size_t)ETOT * 4);
    int*    bsum   = (int*)take((size_t)NBLK * 4);
    int*    boff   = (int*)take((size_t)NBLK * 4);
    __half* albuf16= (__half*)take((size_t)ETOT * NH * 2);
    float*  sums   = (float*)take((size_t)NG * HC * 4);
    int*    gbeg   = (int*)take((size_t)NG * 4);
    int*    gend   = (int*)take((size_t)NG * 4);

    hipMemsetAsync(cnt_n, 0, (size_t)NN * 4, stream);
    hipMemsetAsync(sums, 0, (size_t)NG * HC * 4, stream);
    hipMemsetAsync(gbeg, 0, (size_t)NG * 4, stream);
    hipMemsetAsync(gend, 0, (size_t)NG * 4, stream);

    // CSR + conversions
    count_dst<<<(ETOT + 255) / 256, 256, 0, stream>>>(ei, cnt_n);
    scan_local<<<NBLK, 256, 0, stream>>>(cnt_n, rowptr, bsum);
    scan_bsums<<<1, 256, 0, stream>>>(bsum, boff, rowptr);
    scan_apply<<<NBLK, 256, 0, stream>>>(rowptr, boff, cursor);
    scatter_edges<<<(ETOT + 255) / 256, 256, 0, stream>>>(ei, cursor, csr);
    f32_to_f16_vec<<<(NN * FIN / 4 + 255) / 256, 256, 0, stream>>>(x, x16, NN * FIN / 4);
    w_transpose_f16<<<(FIN * HC + 255) / 256, 256, 0, stream>>>(W1, w1t, FIN);
    w_transpose_f16<<<(HC * HC + 255) / 256, 256, 0, stream>>>(W2, w2t, HC);

    // layer 1
    gemm_f16<<<dim3(2, (NN + 127) / 128), 256, 0, stream>>>(x16, w1t, bufT16, NN, FIN);
    attn_scores<<<(NN + 3) / 4, 256, 0, stream>>>(bufT16, a_src1, a_dst1, es, ed);
    softmax_alpha<<<(NN + 3) / 4, 256, 0, stream>>>(es, ed, rowptr, csr, albuf16);
    gat_gather<<<(NN + 3) / 4, 256, 0, stream>>>(bufT16, albuf16, rowptr, csr, b1, bufH16);

    // layer 2
    gemm_f16<<<dim3(2, (NN + 127) / 128), 256, 0, stream>>>(bufH16, w2t, bufT16, NN, HC);
    attn_scores<<<(NN + 3) / 4, 256, 0, stream>>>(bufT16, a_src2, a_dst2, es, ed);
    softmax_alpha<<<(NN + 3) / 4, 256, 0, stream>>>(es, ed, rowptr, csr, albuf16);
    gat_gather<<<(NN + 3) / 4, 256, 0, stream>>>(bufT16, albuf16, rowptr, csr, b2, bufH16);

    // pool + head
    pool_sum<<<(NN + 127) / 128, 256, 0, stream>>>(bufH16, batch, sums);
    batch_bounds<<<(NN + 255) / 256, 256, 0, stream>>>(batch, gbeg, gend);
    final_linear<<<4, 256, 0, stream>>>(sums, gbeg, gend, Wlin, blin, out);
}

// Round 8
// 384.461 us; speedup vs baseline: 3.0090x; 1.1664x over previous
//
#include <hip/hip_runtime.h>
#include <hip/hip_fp16.h>

#define NN   50000
#define EE   800000
#define ETOT 850000   // EE + NN self loops
#define FIN  128
#define HC   256      // H*C
#define NH   4
#define CH   64
#define NG   64
#define NOUT 16
#define NEG_SLOPE 0.2f

#define NBUCK 391     // ceil(NN/128) dst-range buckets
#define BCAP  4096    // slots per bucket (avg fill ~2176, 40+ sigma headroom)
#define EPB   4096    // edges per phase-1 block
#define NEB   208     // ceil(ETOT/EPB)

typedef _Float16 f16x8 __attribute__((ext_vector_type(8)));
typedef float    f32x4 __attribute__((ext_vector_type(4)));

// ---------------- online softmax combine (sentinel -1e30 avoids NaN) ----------
__device__ __forceinline__ void sm_combine(float& m, float& s, float om, float os) {
    float M = fmaxf(m, om);
    s = s * __expf(m - M) + os * __expf(om - M);
    m = M;
}

// ======== CSR build: 2-phase dst-range bucketing (no global scatter) ========
// phase 1: partition edges into 391 buckets of 128 dst each; packed 4B records
__global__ __launch_bounds__(256) void edge_bucket(const int* __restrict__ ei,
                                                   int* __restrict__ bucket_counts,
                                                   unsigned* __restrict__ buckets) {
    __shared__ int h[NBUCK];
    __shared__ int bb[NBUCK];
    const int tid = threadIdx.x;
    const int e0  = blockIdx.x * EPB;

    for (int t = tid; t < NBUCK; t += 256) h[t] = 0;
    __syncthreads();

    int srcs[16], dsts[16];
#pragma unroll
    for (int k = 0; k < 16; ++k) {
        int i = e0 + k * 256 + tid;
        int s = 0, d = -1;
        if (i < ETOT) {
            s = (i < EE) ? ei[i] : (i - EE);
            d = (i < EE) ? ei[EE + i] : (i - EE);
            atomicAdd(&h[d >> 7], 1);
        }
        srcs[k] = s; dsts[k] = d;
    }
    __syncthreads();

    for (int t = tid; t < NBUCK; t += 256) {
        bb[t] = atomicAdd(&bucket_counts[t], h[t]);   // reserve contiguous run
        h[t]  = 0;
    }
    __syncthreads();

#pragma unroll
    for (int k = 0; k < 16; ++k) {
        int d = dsts[k];
        if (d >= 0) {
            int b = d >> 7;
            int r = atomicAdd(&h[b], 1);
            int idx = bb[b] + r;
            if (idx < BCAP)
                buckets[(size_t)b * BCAP + idx] =
                    (unsigned)srcs[k] | ((unsigned)(d & 127) << 16);
        }
    }
}

// phase 1b: scan 391 bucket counts -> bucket bases
__global__ __launch_bounds__(512) void bucket_scan(const int* __restrict__ counts,
                                                   int* __restrict__ basep,
                                                   int* __restrict__ rowptr) {
    __shared__ int lds[512];
    const int tid = threadIdx.x;
    int v = (tid < NBUCK) ? counts[tid] : 0;
    lds[tid] = v;
    __syncthreads();
    for (int off = 1; off < 512; off <<= 1) {
        int t = (tid >= off) ? lds[tid - off] : 0;
        __syncthreads();
        lds[tid] += t;
        __syncthreads();
    }
    if (tid < NBUCK) basep[tid] = lds[tid] - v;
    if (tid == 0) rowptr[NN] = ETOT;
}

// phase 2: one block per bucket -> rowptr + csr (all writes bucket-local)
__global__ __launch_bounds__(256) void bucket_to_csr(const unsigned* __restrict__ buckets,
                                                     const int* __restrict__ bucket_counts,
                                                     const int* __restrict__ bucket_base,
                                                     int* __restrict__ rowptr,
                                                     int* __restrict__ csr) {
    __shared__ int h[128], c[128], sc[128];
    const int b = blockIdx.x, tid = threadIdx.x;
    const int nb   = bucket_counts[b];
    const int base = bucket_base[b];

    if (tid < 128) h[tid] = 0;
    __syncthreads();
    for (int i = tid; i < nb; i += 256) {
        unsigned p = buckets[(size_t)b * BCAP + i];
        atomicAdd(&h[p >> 16], 1);
    }
    __syncthreads();
    if (tid < 128) sc[tid] = h[tid];
    __syncthreads();
    for (int off = 1; off < 128; off <<= 1) {
        int t = (tid < 128 && tid >= off) ? sc[tid - off] : 0;
        __syncthreads();
        if (tid < 128) sc[tid] += t;
        __syncthreads();
    }
    if (tid < 128) {
        int excl = sc[tid] - h[tid];
        c[tid] = excl;
        int node = (b << 7) + tid;
        if (node < NN) rowptr[node] = base + excl;
    }
    __syncthreads();
    for (int i = tid; i < nb; i += 256) {
        unsigned p = buckets[(size_t)b * BCAP + i];
        int pos = atomicAdd(&c[p >> 16], 1);
        csr[base + pos] = (int)(p & 0xFFFFu);
    }
}

// ---------------- dtype conversions ----------------
__global__ void f32_to_f16_vec(const float* __restrict__ in, __half* __restrict__ out,
                               int n4) {
    int i = blockIdx.x * 256 + threadIdx.x;
    if (i >= n4) return;
    float4 v = *(const float4*)&in[(size_t)i * 4];
    __half h[4] = {__float2half(v.x), __float2half(v.y), __float2half(v.z), __float2half(v.w)};
    *(uint2*)&out[(size_t)i * 4] = *(uint2*)h;
}

// W[K,256] f32 -> Wt[256][K] fp16
__global__ void w_transpose_f16(const float* __restrict__ W, __half* __restrict__ Wt,
                                int K) {
    int idx = blockIdx.x * 256 + threadIdx.x;
    if (idx >= K * HC) return;
    int n = idx / K, k = idx - n * K;
    Wt[idx] = __float2half(W[(size_t)k * HC + n]);
}

// ---- f16 MFMA GEMM: C16[M,256] = A16[M,K] @ Bt16[256,K]^T (fp16 out only) ----
__global__ __launch_bounds__(256) void gemm_f16(const __half* __restrict__ A16,
                                                const __half* __restrict__ Bt16,
                                                __half* __restrict__ C16,
                                                int M, int K) {
    __shared__ char lds[32768];           // As 16KB | Bs 16KB, both [128][64] fp16 swizzled
    const int tid  = threadIdx.x;
    const int m0   = blockIdx.y * 128;
    const int n0   = blockIdx.x * 128;
    const int wid  = tid >> 6, lane = tid & 63;
    const int wr   = wid >> 1, wc = wid & 1;
    const int l15  = lane & 15, l4 = lane >> 4;
    const int trow = tid >> 3;            // 0..31
    const int tcol = (tid & 7) * 8;       // fp16 units within 64-wide k slice

    f32x4 acc[4][4] = {};

    for (int k0 = 0; k0 < K; k0 += 64) {
        __syncthreads();
#pragma unroll
        for (int it = 0; it < 4; ++it) {
            int row = trow + it * 32;
            uint4 v = make_uint4(0u, 0u, 0u, 0u);
            int gr = m0 + row;
            if (gr < M) v = *(const uint4*)&A16[(size_t)gr * K + k0 + tcol];
            int off = (row * 128 + tcol * 2) ^ ((row & 7) << 4);
            *(uint4*)(lds + off) = v;
            uint4 w = *(const uint4*)&Bt16[(size_t)(n0 + row) * K + k0 + tcol];
            int offb = 16384 + ((row * 128 + tcol * 2) ^ ((row & 7) << 4));
            *(uint4*)(lds + offb) = w;
        }
        __syncthreads();
#pragma unroll
        for (int ks = 0; ks < 2; ++ks) {
            f16x8 af[4], bf[4];
#pragma unroll
            for (int i = 0; i < 4; ++i) {
                int rowA = wr * 64 + i * 16 + l15;
                int offA = (rowA * 128 + ks * 64 + l4 * 16) ^ ((rowA & 7) << 4);
                af[i] = *(const f16x8*)(lds + offA);
                int rowB = wc * 64 + i * 16 + l15;
                int offB = 16384 + ((rowB * 128 + ks * 64 + l4 * 16) ^ ((rowB & 7) << 4));
                bf[i] = *(const f16x8*)(lds + offB);
            }
#pragma unroll
            for (int i = 0; i < 4; ++i)
#pragma unroll
                for (int j = 0; j < 4; ++j)
                    acc[i][j] = __builtin_amdgcn_mfma_f32_16x16x32_f16(af[i], bf[j], acc[i][j], 0, 0, 0);
        }
    }
    // epilogue: C/D mapping col=lane&15, row=(lane>>4)*4+reg
#pragma unroll
    for (int i = 0; i < 4; ++i) {
#pragma unroll
        for (int r = 0; r < 4; ++r) {
            int row = m0 + wr * 64 + i * 16 + l4 * 4 + r;
            if (row < M) {
#pragma unroll
                for (int j = 0; j < 4; ++j) {
                    int col = n0 + wc * 64 + j * 16 + l15;
                    C16[(size_t)row * HC + col] = __float2half(acc[i][j][r]);
                }
            }
        }
    }
}

// ---------------- per-node attention scores (fp16 features) ----------------
__global__ __launch_bounds__(256) void attn_scores(const __half* __restrict__ h,
                                                   const float* __restrict__ a_src,
                                                   const float* __restrict__ a_dst,
                                                   float* __restrict__ es,
                                                   float* __restrict__ ed) {
    int node = blockIdx.x * 4 + (threadIdx.x >> 6);
    int lane = threadIdx.x & 63;
    if (node >= NN) return;
#pragma unroll
    for (int hh = 0; hh < NH; ++hh) {
        float v  = __half2float(h[(size_t)node * HC + hh * CH + lane]);
        float ps = v * a_src[hh * CH + lane];
        float pd = v * a_dst[hh * CH + lane];
#pragma unroll
        for (int off = 32; off > 0; off >>= 1) {
            ps += __shfl_xor(ps, off);
            pd += __shfl_xor(pd, off);
        }
        if (lane == 0) {
            es[node * NH + hh] = ps;
            ed[node * NH + hh] = pd;
        }
    }
}

// ---- softmax: wave per node, butterfly reduce, packed-fp16 alpha write ----
__global__ __launch_bounds__(256) void softmax_alpha(const float* __restrict__ es,
                                                     const float* __restrict__ ed,
                                                     const int* __restrict__ rowptr,
                                                     const int* __restrict__ csr_src,
                                                     __half* __restrict__ alpha16) {
    const int node = blockIdx.x * 4 + (threadIdx.x >> 6);
    const int lane = threadIdx.x & 63;
    if (node >= NN) return;
    const int start = rowptr[node];
    const int deg   = rowptr[node + 1] - start;

    float4 ed4 = *(const float4*)&ed[node * NH];
    float edn[NH] = {ed4.x, ed4.y, ed4.z, ed4.w};

    float m[NH], s[NH];
#pragma unroll
    for (int h = 0; h < NH; ++h) { m[h] = -1e30f; s[h] = 0.f; }

    for (int j = lane; j < deg; j += 64) {
        int src = csr_src[start + j];
        float4 e4 = *(const float4*)&es[src * NH];
        float ev[NH] = {e4.x, e4.y, e4.z, e4.w};
#pragma unroll
        for (int h = 0; h < NH; ++h) {
            float e = ev[h] + edn[h];
            e = (e > 0.f) ? e : NEG_SLOPE * e;
            sm_combine(m[h], s[h], e, 1.0f);
        }
    }
#pragma unroll
    for (int h = 0; h < NH; ++h)
#pragma unroll
        for (int off = 32; off > 0; off >>= 1) {
            float om = __shfl_xor(m[h], off);
            float os = __shfl_xor(s[h], off);
            sm_combine(m[h], s[h], om, os);
        }
    float is[NH];
#pragma unroll
    for (int h = 0; h < NH; ++h) is[h] = 1.0f / s[h];

    for (int j = lane; j < deg; j += 64) {
        int src = csr_src[start + j];
        float4 e4 = *(const float4*)&es[src * NH];
        float ev[NH] = {e4.x, e4.y, e4.z, e4.w};
        __half ah[4];
#pragma unroll
        for (int h = 0; h < NH; ++h) {
            float e = ev[h] + edn[h];
            e = (e > 0.f) ? e : NEG_SLOPE * e;
            ah[h] = __float2half(__expf(e - m[h]) * is[h]);
        }
        *(uint2*)&alpha16[(size_t)(start + j) * NH] = *(uint2*)ah;
    }
}

// ------- gather: one wave per node, fp16 features, unroll-4 MLP -------
__global__ __launch_bounds__(256) void gat_gather(const __half* __restrict__ hfeat,
                                                  const __half* __restrict__ alpha16,
                                                  const int* __restrict__ rowptr,
                                                  const int* __restrict__ csr_src,
                                                  const float* __restrict__ bias,
                                                  __half* __restrict__ out16) {
    const int node = blockIdx.x * 4 + (threadIdx.x >> 6);
    const int lane = threadIdx.x & 63;
    if (node >= NN) return;
    const int start = rowptr[node];
    const int deg   = rowptr[node + 1] - start;
    const int hsel  = lane >> 4;   // head for this lane's 4 channels

    float4 acc = make_float4(0.f, 0.f, 0.f, 0.f);
    int j = 0;
    for (; j + 3 < deg; j += 4) {
        const int e = start + j;
        int s0 = csr_src[e + 0];
        int s1 = csr_src[e + 1];
        int s2 = csr_src[e + 2];
        int s3 = csr_src[e + 3];
        float a0 = __half2float(alpha16[(size_t)(e + 0) * NH + hsel]);
        float a1 = __half2float(alpha16[(size_t)(e + 1) * NH + hsel]);
        float a2 = __half2float(alpha16[(size_t)(e + 2) * NH + hsel]);
        float a3 = __half2float(alpha16[(size_t)(e + 3) * NH + hsel]);
        uint2 r0 = *(const uint2*)&hfeat[(size_t)s0 * HC + lane * 4];
        uint2 r1 = *(const uint2*)&hfeat[(size_t)s1 * HC + lane * 4];
        uint2 r2 = *(const uint2*)&hfeat[(size_t)s2 * HC + lane * 4];
        uint2 r3 = *(const uint2*)&hfeat[(size_t)s3 * HC + lane * 4];
        float2 f0a = __half22float2(*reinterpret_cast<__half2*>(&r0.x));
        float2 f0b = __half22float2(*reinterpret_cast<__half2*>(&r0.y));
        float2 f1a = __half22float2(*reinterpret_cast<__half2*>(&r1.x));
        float2 f1b = __half22float2(*reinterpret_cast<__half2*>(&r1.y));
        float2 f2a = __half22float2(*reinterpret_cast<__half2*>(&r2.x));
        float2 f2b = __half22float2(*reinterpret_cast<__half2*>(&r2.y));
        float2 f3a = __half22float2(*reinterpret_cast<__half2*>(&r3.x));
        float2 f3b = __half22float2(*reinterpret_cast<__half2*>(&r3.y));
        acc.x = fmaf(a0, f0a.x, acc.x); acc.y = fmaf(a0, f0a.y, acc.y);
        acc.z = fmaf(a0, f0b.x, acc.z); acc.w = fmaf(a0, f0b.y, acc.w);
        acc.x = fmaf(a1, f1a.x, acc.x); acc.y = fmaf(a1, f1a.y, acc.y);
        acc.z = fmaf(a1, f1b.x, acc.z); acc.w = fmaf(a1, f1b.y, acc.w);
        acc.x = fmaf(a2, f2a.x, acc.x); acc.y = fmaf(a2, f2a.y, acc.y);
        acc.z = fmaf(a2, f2b.x, acc.z); acc.w = fmaf(a2, f2b.y, acc.w);
        acc.x = fmaf(a3, f3a.x, acc.x); acc.y = fmaf(a3, f3a.y, acc.y);
        acc.z = fmaf(a3, f3b.x, acc.z); acc.w = fmaf(a3, f3b.y, acc.w);
    }
    for (; j < deg; ++j) {
        const int e = start + j;
        int s0 = csr_src[e];
        float a0 = __half2float(alpha16[(size_t)e * NH + hsel]);
        uint2 r0 = *(const uint2*)&hfeat[(size_t)s0 * HC + lane * 4];
        float2 f0a = __half22float2(*reinterpret_cast<__half2*>(&r0.x));
        float2 f0b = __half22float2(*reinterpret_cast<__half2*>(&r0.y));
        acc.x = fmaf(a0, f0a.x, acc.x); acc.y = fmaf(a0, f0a.y, acc.y);
        acc.z = fmaf(a0, f0b.x, acc.z); acc.w = fmaf(a0, f0b.y, acc.w);
    }
    float4 b4 = *(const float4*)&bias[lane * 4];
    __half h[4];
    h[0] = __float2half(fmaxf(acc.x + b4.x, 0.f));
    h[1] = __float2half(fmaxf(acc.y + b4.y, 0.f));
    h[2] = __float2half(fmaxf(acc.z + b4.z, 0.f));
    h[3] = __float2half(fmaxf(acc.w + b4.w, 0.f));
    *(uint2*)&out16[(size_t)node * HC + lane * 4] = *(uint2*)h;
}

// ---------------- mean pool + final linear ----------------
__global__ __launch_bounds__(256) void pool_sum(const __half* __restrict__ h,
                                                const int* __restrict__ batch,
                                                float* __restrict__ sums) {
    int t  = threadIdx.x;
    int n0 = blockIdx.x * 128;
    if (n0 >= NN) return;
    int cur = batch[n0];
    float acc = 0.f;
    int nend = min(n0 + 128, NN);
    for (int n = n0; n < nend; ++n) {
        int g = batch[n];
        if (g != cur) {
            atomicAdd(&sums[cur * HC + t], acc);
            acc = 0.f; cur = g;
        }
        acc += __half2float(h[(size_t)n * HC + t]);
    }
    atomicAdd(&sums[cur * HC + t], acc);
}

// ---- group bounds from sorted batch: no atomics ----
__global__ void batch_bounds(const int* __restrict__ batch,
                             int* __restrict__ beg, int* __restrict__ end) {
    int i = blockIdx.x * 256 + threadIdx.x;
    if (i >= NN) return;
    int g = batch[i];
    if (i == 0      || batch[i - 1] != g) beg[g] = i;
    if (i == NN - 1 || batch[i + 1] != g) end[g] = i + 1;
}

__global__ __launch_bounds__(256) void final_linear(const float* __restrict__ sums,
                                                    const int* __restrict__ beg,
                                                    const int* __restrict__ end,
                                                    const float* __restrict__ Wlin,
                                                    const float* __restrict__ blin,
                                                    float* __restrict__ out) {
    int idx = blockIdx.x * 256 + threadIdx.x;   // 0..1023
    if (idx >= NG * NOUT) return;
    int g = idx >> 4, o = idx & 15;
    float cnt = (float)(end[g] - beg[g]);
    float invc = 1.f / fmaxf(cnt, 1.f);
    float acc = 0.f;
    for (int k = 0; k < HC; ++k) acc += sums[g * HC + k] * Wlin[k * NOUT + o];
    out[idx] = acc * invc + blin[o];
}

// ---------------- launch ----------------
extern "C" void kernel_launch(void* const* d_in, const int* in_sizes, int n_in,
                              void* d_out, int out_size, void* d_ws, size_t ws_size,
                              hipStream_t stream) {
    const float* x      = (const float*)d_in[0];
    const int*   ei     = (const int*)d_in[1];
    const int*   batch  = (const int*)d_in[2];
    const float* W1     = (const float*)d_in[3];
    const float* a_src1 = (const float*)d_in[4];
    const float* a_dst1 = (const float*)d_in[5];
    const float* b1     = (const float*)d_in[6];
    const float* W2     = (const float*)d_in[7];
    const float* a_src2 = (const float*)d_in[8];
    const float* a_dst2 = (const float*)d_in[9];
    const float* b2     = (const float*)d_in[10];
    const float* Wlin   = (const float*)d_in[11];
    const float* blin   = (const float*)d_in[12];
    float* out = (float*)d_out;

    char* p = (char*)d_ws;
    auto take = [&](size_t bytes) {
        char* r = p;
        p += (bytes + 255) & ~(size_t)255;
        return r;
    };
    __half*   bufT16 = (__half*)take((size_t)NN * HC * 2);
    __half*   bufH16 = (__half*)take((size_t)NN * HC * 2);
    __half*   x16    = (__half*)take((size_t)NN * FIN * 2);
    __half*   w1t    = (__half*)take((size_t)FIN * HC * 2);
    __half*   w2t    = (__half*)take((size_t)HC * HC * 2);
    float*    es     = (float*)take((size_t)NN * NH * 4);
    float*    ed     = (float*)take((size_t)NN * NH * 4);
    int*      rowptr = (int*)take((size_t)(NN + 1) * 4);
    int*      csr    = (int*)take((size_t)ETOT * 4);
    unsigned* buckets= (unsigned*)take((size_t)NBUCK * BCAP * 4);
    int*      bcnt   = (int*)take((size_t)NBUCK * 4);
    int*      bbase  = (int*)take((size_t)NBUCK * 4);
    __half*   albuf16= (__half*)take((size_t)ETOT * NH * 2);
    float*    sums   = (float*)take((size_t)NG * HC * 4);
    int*      gbeg   = (int*)take((size_t)NG * 4);
    int*      gend   = (int*)take((size_t)NG * 4);

    hipMemsetAsync(bcnt, 0, (size_t)NBUCK * 4, stream);
    hipMemsetAsync(sums, 0, (size_t)NG * HC * 4, stream);
    hipMemsetAsync(gbeg, 0, (size_t)NG * 4, stream);
    hipMemsetAsync(gend, 0, (size_t)NG * 4, stream);

    // CSR build (bucketed) + conversions
    edge_bucket<<<NEB, 256, 0, stream>>>(ei, bcnt, buckets);
    bucket_scan<<<1, 512, 0, stream>>>(bcnt, bbase, rowptr);
    bucket_to_csr<<<NBUCK, 256, 0, stream>>>(buckets, bcnt, bbase, rowptr, csr);
    f32_to_f16_vec<<<(NN * FIN / 4 + 255) / 256, 256, 0, stream>>>(x, x16, NN * FIN / 4);
    w_transpose_f16<<<(FIN * HC + 255) / 256, 256, 0, stream>>>(W1, w1t, FIN);
    w_transpose_f16<<<(HC * HC + 255) / 256, 256, 0, stream>>>(W2, w2t, HC);

    // layer 1
    gemm_f16<<<dim3(2, (NN + 127) / 128), 256, 0, stream>>>(x16, w1t, bufT16, NN, FIN);
    attn_scores<<<(NN + 3) / 4, 256, 0, stream>>>(bufT16, a_src1, a_dst1, es, ed);
    softmax_alpha<<<(NN + 3) / 4, 256, 0, stream>>>(es, ed, rowptr, csr, albuf16);
    gat_gather<<<(NN + 3) / 4, 256, 0, stream>>>(bufT16, albuf16, rowptr, csr, b1, bufH16);

    // layer 2
    gemm_f16<<<dim3(2, (NN + 127) / 128), 256, 0, stream>>>(bufH16, w2t, bufT16, NN, HC);
    attn_scores<<<(NN + 3) / 4, 256, 0, stream>>>(bufT16, a_src2, a_dst2, es, ed);
    softmax_alpha<<<(NN + 3) / 4, 256, 0, stream>>>(es, ed, rowptr, csr, albuf16);
    gat_gather<<<(NN + 3) / 4, 256, 0, stream>>>(bufT16, albuf16, rowptr, csr, b2, bufH16);

    // pool + head
    pool_sum<<<(NN + 127) / 128, 256, 0, stream>>>(bufH16, batch, sums);
    batch_bounds<<<(NN + 255) / 256, 256, 0, stream>>>(batch, gbeg, gend);
    final_linear<<<4, 256, 0, stream>>>(sums, gbeg, gend, Wlin, blin, out);
}

// Round 9
// 348.126 us; speedup vs baseline: 3.3230x; 1.1044x over previous
//
#include <hip/hip_runtime.h>
#include <hip/hip_fp16.h>

#define NN   50000
#define EE   800000
#define ETOT 850000   // EE + NN self loops
#define FIN  128
#define HC   256      // H*C
#define NH   4
#define CH   64
#define NG   64
#define NOUT 16
#define NEG_SLOPE 0.2f

#define NBUCK 391     // ceil(NN/128) dst-range buckets
#define BCAP  4096    // slots per bucket (avg fill ~2176, 40+ sigma headroom)
#define EPB   4096    // edges per phase-1 block
#define NEB   208     // ceil(ETOT/EPB)

typedef _Float16 f16x8 __attribute__((ext_vector_type(8)));
typedef float    f32x4 __attribute__((ext_vector_type(4)));

// ---------------- online softmax combine (sentinel -1e30 avoids NaN) ----------
__device__ __forceinline__ void sm_combine(float& m, float& s, float om, float os) {
    float M = fmaxf(m, om);
    s = s * __expf(m - M) + os * __expf(om - M);
    m = M;
}

// ======== CSR build: 2-phase dst-range bucketing (no global scatter) ========
__global__ __launch_bounds__(256) void edge_bucket(const int* __restrict__ ei,
                                                   int* __restrict__ bucket_counts,
                                                   unsigned* __restrict__ buckets) {
    __shared__ int h[NBUCK];
    __shared__ int bb[NBUCK];
    const int tid = threadIdx.x;
    const int e0  = blockIdx.x * EPB;

    for (int t = tid; t < NBUCK; t += 256) h[t] = 0;
    __syncthreads();

    int srcs[16], dsts[16];
#pragma unroll
    for (int k = 0; k < 16; ++k) {
        int i = e0 + k * 256 + tid;
        int s = 0, d = -1;
        if (i < ETOT) {
            s = (i < EE) ? ei[i] : (i - EE);
            d = (i < EE) ? ei[EE + i] : (i - EE);
            atomicAdd(&h[d >> 7], 1);
        }
        srcs[k] = s; dsts[k] = d;
    }
    __syncthreads();

    for (int t = tid; t < NBUCK; t += 256) {
        bb[t] = atomicAdd(&bucket_counts[t], h[t]);   // reserve contiguous run
        h[t]  = 0;
    }
    __syncthreads();

#pragma unroll
    for (int k = 0; k < 16; ++k) {
        int d = dsts[k];
        if (d >= 0) {
            int b = d >> 7;
            int r = atomicAdd(&h[b], 1);
            int idx = bb[b] + r;
            if (idx < BCAP)
                buckets[(size_t)b * BCAP + idx] =
                    (unsigned)srcs[k] | ((unsigned)(d & 127) << 16);
        }
    }
}

__global__ __launch_bounds__(512) void bucket_scan(const int* __restrict__ counts,
                                                   int* __restrict__ basep,
                                                   int* __restrict__ rowptr) {
    __shared__ int lds[512];
    const int tid = threadIdx.x;
    int v = (tid < NBUCK) ? counts[tid] : 0;
    lds[tid] = v;
    __syncthreads();
    for (int off = 1; off < 512; off <<= 1) {
        int t = (tid >= off) ? lds[tid - off] : 0;
        __syncthreads();
        lds[tid] += t;
        __syncthreads();
    }
    if (tid < NBUCK) basep[tid] = lds[tid] - v;
    if (tid == 0) rowptr[NN] = ETOT;
}

__global__ __launch_bounds__(256) void bucket_to_csr(const unsigned* __restrict__ buckets,
                                                     const int* __restrict__ bucket_counts,
                                                     const int* __restrict__ bucket_base,
                                                     int* __restrict__ rowptr,
                                                     int* __restrict__ csr) {
    __shared__ int h[128], c[128], sc[128];
    const int b = blockIdx.x, tid = threadIdx.x;
    const int nb   = bucket_counts[b];
    const int base = bucket_base[b];

    if (tid < 128) h[tid] = 0;
    __syncthreads();
    for (int i = tid; i < nb; i += 256) {
        unsigned p = buckets[(size_t)b * BCAP + i];
        atomicAdd(&h[p >> 16], 1);
    }
    __syncthreads();
    if (tid < 128) sc[tid] = h[tid];
    __syncthreads();
    for (int off = 1; off < 128; off <<= 1) {
        int t = (tid < 128 && tid >= off) ? sc[tid - off] : 0;
        __syncthreads();
        if (tid < 128) sc[tid] += t;
        __syncthreads();
    }
    if (tid < 128) {
        int excl = sc[tid] - h[tid];
        c[tid] = excl;
        int node = (b << 7) + tid;
        if (node < NN) rowptr[node] = base + excl;
    }
    __syncthreads();
    for (int i = tid; i < nb; i += 256) {
        unsigned p = buckets[(size_t)b * BCAP + i];
        int pos = atomicAdd(&c[p >> 16], 1);
        csr[base + pos] = (int)(p & 0xFFFFu);
    }
}

// ---------------- dtype conversions ----------------
__global__ void f32_to_f16_vec(const float* __restrict__ in, __half* __restrict__ out,
                               int n4) {
    int i = blockIdx.x * 256 + threadIdx.x;
    if (i >= n4) return;
    float4 v = *(const float4*)&in[(size_t)i * 4];
    __half h[4] = {__float2half(v.x), __float2half(v.y), __float2half(v.z), __float2half(v.w)};
    *(uint2*)&out[(size_t)i * 4] = *(uint2*)h;
}

// W[K,256] f32 -> Wt[256][K] fp16
__global__ void w_transpose_f16(const float* __restrict__ W, __half* __restrict__ Wt,
                                int K) {
    int idx = blockIdx.x * 256 + threadIdx.x;
    if (idx >= K * HC) return;
    int n = idx / K, k = idx - n * K;
    Wt[idx] = __float2half(W[(size_t)k * HC + n]);
}

// ---- f16 MFMA GEMM + fused attention-score epilogue ----
// C16[M,256] = A16 @ Bt16^T; es/ed[row][head] = dot(C_row_head, a_src/dst_head)
__global__ __launch_bounds__(256) void gemm_f16(const __half* __restrict__ A16,
                                                const __half* __restrict__ Bt16,
                                                __half* __restrict__ C16,
                                                const float* __restrict__ a_src,
                                                const float* __restrict__ a_dst,
                                                float* __restrict__ es,
                                                float* __restrict__ ed,
                                                int M, int K) {
    __shared__ char lds[32768];           // As 16KB | Bs 16KB, both [128][64] fp16 swizzled
    const int tid  = threadIdx.x;
    const int m0   = blockIdx.y * 128;
    const int n0   = blockIdx.x * 128;
    const int wid  = tid >> 6, lane = tid & 63;
    const int wr   = wid >> 1, wc = wid & 1;
    const int l15  = lane & 15, l4 = lane >> 4;
    const int trow = tid >> 3;            // 0..31
    const int tcol = (tid & 7) * 8;       // fp16 units within 64-wide k slice

    f32x4 acc[4][4] = {};

    for (int k0 = 0; k0 < K; k0 += 64) {
        __syncthreads();
#pragma unroll
        for (int it = 0; it < 4; ++it) {
            int row = trow + it * 32;
            uint4 v = make_uint4(0u, 0u, 0u, 0u);
            int gr = m0 + row;
            if (gr < M) v = *(const uint4*)&A16[(size_t)gr * K + k0 + tcol];
            int off = (row * 128 + tcol * 2) ^ ((row & 7) << 4);
            *(uint4*)(lds + off) = v;
            uint4 w = *(const uint4*)&Bt16[(size_t)(n0 + row) * K + k0 + tcol];
            int offb = 16384 + ((row * 128 + tcol * 2) ^ ((row & 7) << 4));
            *(uint4*)(lds + offb) = w;
        }
        __syncthreads();
#pragma unroll
        for (int ks = 0; ks < 2; ++ks) {
            f16x8 af[4], bf[4];
#pragma unroll
            for (int i = 0; i < 4; ++i) {
                int rowA = wr * 64 + i * 16 + l15;
                int offA = (rowA * 128 + ks * 64 + l4 * 16) ^ ((rowA & 7) << 4);
                af[i] = *(const f16x8*)(lds + offA);
                int rowB = wc * 64 + i * 16 + l15;
                int offB = 16384 + ((rowB * 128 + ks * 64 + l4 * 16) ^ ((rowB & 7) << 4));
                bf[i] = *(const f16x8*)(lds + offB);
            }
#pragma unroll
            for (int i = 0; i < 4; ++i)
#pragma unroll
                for (int j = 0; j < 4; ++j)
                    acc[i][j] = __builtin_amdgcn_mfma_f32_16x16x32_f16(af[i], bf[j], acc[i][j], 0, 0, 0);
        }
    }
    // epilogue 1: C store (C/D mapping col=lane&15, row=(lane>>4)*4+reg)
#pragma unroll
    for (int i = 0; i < 4; ++i) {
#pragma unroll
        for (int r = 0; r < 4; ++r) {
            int row = m0 + wr * 64 + i * 16 + l4 * 4 + r;
            if (row < M) {
#pragma unroll
                for (int j = 0; j < 4; ++j) {
                    int col = n0 + wc * 64 + j * 16 + l15;
                    C16[(size_t)row * HC + col] = __float2half(acc[i][j][r]);
                }
            }
        }
    }
    // epilogue 2: fused attention scores. This wave's 64 cols == one head.
    const int hd = blockIdx.x * 2 + wc;
    float as_[4], ad_[4];
#pragma unroll
    for (int j = 0; j < 4; ++j) {
        int c = j * 16 + l15;
        as_[j] = a_src[hd * CH + c];
        ad_[j] = a_dst[hd * CH + c];
    }
#pragma unroll
    for (int i = 0; i < 4; ++i) {
#pragma unroll
        for (int r = 0; r < 4; ++r) {
            float ps = 0.f, pd = 0.f;
#pragma unroll
            for (int j = 0; j < 4; ++j) {
                ps = fmaf(acc[i][j][r], as_[j], ps);
                pd = fmaf(acc[i][j][r], ad_[j], pd);
            }
#pragma unroll
            for (int mm = 8; mm; mm >>= 1) {
                ps += __shfl_xor(ps, mm);
                pd += __shfl_xor(pd, mm);
            }
            int row = m0 + wr * 64 + i * 16 + l4 * 4 + r;
            if (l15 == 0 && row < M) {
                es[row * NH + hd] = ps;
                ed[row * NH + hd] = pd;
            }
        }
    }
}

// ---- softmax: wave per node, butterfly reduce, packed-fp16 alpha write ----
__global__ __launch_bounds__(256) void softmax_alpha(const float* __restrict__ es,
                                                     const float* __restrict__ ed,
                                                     const int* __restrict__ rowptr,
                                                     const int* __restrict__ csr_src,
                                                     __half* __restrict__ alpha16) {
    const int node = blockIdx.x * 4 + (threadIdx.x >> 6);
    const int lane = threadIdx.x & 63;
    if (node >= NN) return;
    const int start = rowptr[node];
    const int deg   = rowptr[node + 1] - start;

    float4 ed4 = *(const float4*)&ed[node * NH];
    float edn[NH] = {ed4.x, ed4.y, ed4.z, ed4.w};

    float m[NH], s[NH];
#pragma unroll
    for (int h = 0; h < NH; ++h) { m[h] = -1e30f; s[h] = 0.f; }

    for (int j = lane; j < deg; j += 64) {
        int src = csr_src[start + j];
        float4 e4 = *(const float4*)&es[src * NH];
        float ev[NH] = {e4.x, e4.y, e4.z, e4.w};
#pragma unroll
        for (int h = 0; h < NH; ++h) {
            float e = ev[h] + edn[h];
            e = (e > 0.f) ? e : NEG_SLOPE * e;
            sm_combine(m[h], s[h], e, 1.0f);
        }
    }
#pragma unroll
    for (int h = 0; h < NH; ++h)
#pragma unroll
        for (int off = 32; off > 0; off >>= 1) {
            float om = __shfl_xor(m[h], off);
            float os = __shfl_xor(s[h], off);
            sm_combine(m[h], s[h], om, os);
        }
    float is[NH];
#pragma unroll
    for (int h = 0; h < NH; ++h) is[h] = 1.0f / s[h];

    for (int j = lane; j < deg; j += 64) {
        int src = csr_src[start + j];
        float4 e4 = *(const float4*)&es[src * NH];
        float ev[NH] = {e4.x, e4.y, e4.z, e4.w};
        __half ah[4];
#pragma unroll
        for (int h = 0; h < NH; ++h) {
            float e = ev[h] + edn[h];
            e = (e > 0.f) ? e : NEG_SLOPE * e;
            ah[h] = __float2half(__expf(e - m[h]) * is[h]);
        }
        *(uint2*)&alpha16[(size_t)(start + j) * NH] = *(uint2*)ah;
    }
}

// ------- gather: one wave per node, fp16 features, unroll-8 MLP -------
__global__ __launch_bounds__(256) void gat_gather(const __half* __restrict__ hfeat,
                                                  const __half* __restrict__ alpha16,
                                                  const int* __restrict__ rowptr,
                                                  const int* __restrict__ csr_src,
                                                  const float* __restrict__ bias,
                                                  __half* __restrict__ out16) {
    const int node = blockIdx.x * 4 + (threadIdx.x >> 6);
    const int lane = threadIdx.x & 63;
    if (node >= NN) return;
    const int start = rowptr[node];
    const int deg   = rowptr[node + 1] - start;
    const int hsel  = lane >> 4;   // head for this lane's 4 channels

    float4 acc = make_float4(0.f, 0.f, 0.f, 0.f);
    int j = 0;
    for (; j + 7 < deg; j += 8) {
        const int e = start + j;
        int   idx[8];
        float a[8];
        uint2 r[8];
#pragma unroll
        for (int k = 0; k < 8; ++k) idx[k] = csr_src[e + k];
#pragma unroll
        for (int k = 0; k < 8; ++k) a[k] = __half2float(alpha16[(size_t)(e + k) * NH + hsel]);
#pragma unroll
        for (int k = 0; k < 8; ++k) r[k] = *(const uint2*)&hfeat[(size_t)idx[k] * HC + lane * 4];
#pragma unroll
        for (int k = 0; k < 8; ++k) {
            float2 fa = __half22float2(*reinterpret_cast<__half2*>(&r[k].x));
            float2 fb = __half22float2(*reinterpret_cast<__half2*>(&r[k].y));
            acc.x = fmaf(a[k], fa.x, acc.x); acc.y = fmaf(a[k], fa.y, acc.y);
            acc.z = fmaf(a[k], fb.x, acc.z); acc.w = fmaf(a[k], fb.y, acc.w);
        }
    }
    for (; j < deg; ++j) {
        const int e = start + j;
        int s0 = csr_src[e];
        float a0 = __half2float(alpha16[(size_t)e * NH + hsel]);
        uint2 r0 = *(const uint2*)&hfeat[(size_t)s0 * HC + lane * 4];
        float2 f0a = __half22float2(*reinterpret_cast<__half2*>(&r0.x));
        float2 f0b = __half22float2(*reinterpret_cast<__half2*>(&r0.y));
        acc.x = fmaf(a0, f0a.x, acc.x); acc.y = fmaf(a0, f0a.y, acc.y);
        acc.z = fmaf(a0, f0b.x, acc.z); acc.w = fmaf(a0, f0b.y, acc.w);
    }
    float4 b4 = *(const float4*)&bias[lane * 4];
    __half h[4];
    h[0] = __float2half(fmaxf(acc.x + b4.x, 0.f));
    h[1] = __float2half(fmaxf(acc.y + b4.y, 0.f));
    h[2] = __float2half(fmaxf(acc.z + b4.z, 0.f));
    h[3] = __float2half(fmaxf(acc.w + b4.w, 0.f));
    *(uint2*)&out16[(size_t)node * HC + lane * 4] = *(uint2*)h;
}

// ---------------- mean pool + final linear ----------------
__global__ __launch_bounds__(256) void pool_sum(const __half* __restrict__ h,
                                                const int* __restrict__ batch,
                                                float* __restrict__ sums) {
    int t  = threadIdx.x;
    int n0 = blockIdx.x * 128;
    if (n0 >= NN) return;
    int cur = batch[n0];
    float acc = 0.f;
    int nend = min(n0 + 128, NN);
    for (int n = n0; n < nend; ++n) {
        int g = batch[n];
        if (g != cur) {
            atomicAdd(&sums[cur * HC + t], acc);
            acc = 0.f; cur = g;
        }
        acc += __half2float(h[(size_t)n * HC + t]);
    }
    atomicAdd(&sums[cur * HC + t], acc);
}

// ---- group bounds from sorted batch: no atomics ----
__global__ void batch_bounds(const int* __restrict__ batch,
                             int* __restrict__ beg, int* __restrict__ end) {
    int i = blockIdx.x * 256 + threadIdx.x;
    if (i >= NN) return;
    int g = batch[i];
    if (i == 0      || batch[i - 1] != g) beg[g] = i;
    if (i == NN - 1 || batch[i + 1] != g) end[g] = i + 1;
}

__global__ __launch_bounds__(256) void final_linear(const float* __restrict__ sums,
                                                    const int* __restrict__ beg,
                                                    const int* __restrict__ end,
                                                    const float* __restrict__ Wlin,
                                                    const float* __restrict__ blin,
                                                    float* __restrict__ out) {
    int idx = blockIdx.x * 256 + threadIdx.x;   // 0..1023
    if (idx >= NG * NOUT) return;
    int g = idx >> 4, o = idx & 15;
    float cnt = (float)(end[g] - beg[g]);
    float invc = 1.f / fmaxf(cnt, 1.f);
    float acc = 0.f;
    for (int k = 0; k < HC; ++k) acc += sums[g * HC + k] * Wlin[k * NOUT + o];
    out[idx] = acc * invc + blin[o];
}

// ---------------- launch ----------------
extern "C" void kernel_launch(void* const* d_in, const int* in_sizes, int n_in,
                              void* d_out, int out_size, void* d_ws, size_t ws_size,
                              hipStream_t stream) {
    const float* x      = (const float*)d_in[0];
    const int*   ei     = (const int*)d_in[1];
    const int*   batch  = (const int*)d_in[2];
    const float* W1     = (const float*)d_in[3];
    const float* a_src1 = (const float*)d_in[4];
    const float* a_dst1 = (const float*)d_in[5];
    const float* b1     = (const float*)d_in[6];
    const float* W2     = (const float*)d_in[7];
    const float* a_src2 = (const float*)d_in[8];
    const float* a_dst2 = (const float*)d_in[9];
    const float* b2     = (const float*)d_in[10];
    const float* Wlin   = (const float*)d_in[11];
    const float* blin   = (const float*)d_in[12];
    float* out = (float*)d_out;

    char* p = (char*)d_ws;
    auto take = [&](size_t bytes) {
        char* r = p;
        p += (bytes + 255) & ~(size_t)255;
        return r;
    };
    __half*   bufT16 = (__half*)take((size_t)NN * HC * 2);
    __half*   bufH16 = (__half*)take((size_t)NN * HC * 2);
    __half*   x16    = (__half*)take((size_t)NN * FIN * 2);
    __half*   w1t    = (__half*)take((size_t)FIN * HC * 2);
    __half*   w2t    = (__half*)take((size_t)HC * HC * 2);
    float*    es     = (float*)take((size_t)NN * NH * 4);
    float*    ed     = (float*)take((size_t)NN * NH * 4);
    int*      rowptr = (int*)take((size_t)(NN + 1) * 4);
    int*      csr    = (int*)take((size_t)ETOT * 4);
    unsigned* buckets= (unsigned*)take((size_t)NBUCK * BCAP * 4);
    int*      bcnt   = (int*)take((size_t)NBUCK * 4);
    int*      bbase  = (int*)take((size_t)NBUCK * 4);
    __half*   albuf16= (__half*)take((size_t)ETOT * NH * 2);
    float*    sums   = (float*)take((size_t)NG * HC * 4);
    int*      gbeg   = (int*)take((size_t)NG * 4);
    int*      gend   = (int*)take((size_t)NG * 4);

    hipMemsetAsync(bcnt, 0, (size_t)NBUCK * 4, stream);
    hipMemsetAsync(sums, 0, (size_t)NG * HC * 4, stream);
    hipMemsetAsync(gbeg, 0, (size_t)NG * 4, stream);
    hipMemsetAsync(gend, 0, (size_t)NG * 4, stream);

    // CSR build (bucketed) + conversions
    edge_bucket<<<NEB, 256, 0, stream>>>(ei, bcnt, buckets);
    bucket_scan<<<1, 512, 0, stream>>>(bcnt, bbase, rowptr);
    bucket_to_csr<<<NBUCK, 256, 0, stream>>>(buckets, bcnt, bbase, rowptr, csr);
    f32_to_f16_vec<<<(NN * FIN / 4 + 255) / 256, 256, 0, stream>>>(x, x16, NN * FIN / 4);
    w_transpose_f16<<<(FIN * HC + 255) / 256, 256, 0, stream>>>(W1, w1t, FIN);
    w_transpose_f16<<<(HC * HC + 255) / 256, 256, 0, stream>>>(W2, w2t, HC);

    // layer 1
    gemm_f16<<<dim3(2, (NN + 127) / 128), 256, 0, stream>>>(x16, w1t, bufT16,
                                                            a_src1, a_dst1, es, ed, NN, FIN);
    softmax_alpha<<<(NN + 3) / 4, 256, 0, stream>>>(es, ed, rowptr, csr, albuf16);
    gat_gather<<<(NN + 3) / 4, 256, 0, stream>>>(bufT16, albuf16, rowptr, csr, b1, bufH16);

    // layer 2
    gemm_f16<<<dim3(2, (NN + 127) / 128), 256, 0, stream>>>(bufH16, w2t, bufT16,
                                                            a_src2, a_dst2, es, ed, NN, HC);
    softmax_alpha<<<(NN + 3) / 4, 256, 0, stream>>>(es, ed, rowptr, csr, albuf16);
    gat_gather<<<(NN + 3) / 4, 256, 0, stream>>>(bufT16, albuf16, rowptr, csr, b2, bufH16);

    // pool + head
    pool_sum<<<(NN + 127) / 128, 256, 0, stream>>>(bufH16, batch, sums);
    batch_bounds<<<(NN + 255) / 256, 256, 0, stream>>>(batch, gbeg, gend);
    final_linear<<<4, 256, 0, stream>>>(sums, gbeg, gend, Wlin, blin, out);
}

// Round 10
// 291.153 us; speedup vs baseline: 3.9733x; 1.1957x over previous
//
#include <hip/hip_runtime.h>
#include <hip/hip_fp16.h>

#define NN   50000
#define EE   800000
#define ETOT 850000   // EE + NN self loops
#define FIN  128
#define HC   256      // H*C
#define NH   4
#define CH   64
#define NG   64
#define NOUT 16
#define NEG_SLOPE 0.2f

#define NBUCK 391     // ceil(NN/128) dst-range buckets
#define BCAP  4096    // slots per bucket
#define EPB   4096    // edges per phase-1 block
#define NEB   208     // ceil(ETOT/EPB)

typedef _Float16 f16x8 __attribute__((ext_vector_type(8)));
typedef float    f32x4 __attribute__((ext_vector_type(4)));

__device__ __forceinline__ void sm_combine(float& m, float& s, float om, float os) {
    float M = fmaxf(m, om);
    s = s * __expf(m - M) + os * __expf(om - M);
    m = M;
}

// ======== CSR build: 2-phase dst-range bucketing ========
__global__ __launch_bounds__(256) void edge_bucket(const int* __restrict__ ei,
                                                   int* __restrict__ bucket_counts,
                                                   unsigned* __restrict__ buckets) {
    __shared__ int h[NBUCK];
    __shared__ int bb[NBUCK];
    const int tid = threadIdx.x;
    const int e0  = blockIdx.x * EPB;

    for (int t = tid; t < NBUCK; t += 256) h[t] = 0;
    __syncthreads();

    int srcs[16], dsts[16];
#pragma unroll
    for (int k = 0; k < 16; ++k) {
        int i = e0 + k * 256 + tid;
        int s = 0, d = -1;
        if (i < ETOT) {
            s = (i < EE) ? ei[i] : (i - EE);
            d = (i < EE) ? ei[EE + i] : (i - EE);
            atomicAdd(&h[d >> 7], 1);
        }
        srcs[k] = s; dsts[k] = d;
    }
    __syncthreads();

    for (int t = tid; t < NBUCK; t += 256) {
        bb[t] = atomicAdd(&bucket_counts[t], h[t]);
        h[t]  = 0;
    }
    __syncthreads();

#pragma unroll
    for (int k = 0; k < 16; ++k) {
        int d = dsts[k];
        if (d >= 0) {
            int b = d >> 7;
            int r = atomicAdd(&h[b], 1);
            int idx = bb[b] + r;
            if (idx < BCAP)
                buckets[(size_t)b * BCAP + idx] =
                    (unsigned)srcs[k] | ((unsigned)(d & 127) << 16);
        }
    }
}

__global__ __launch_bounds__(512) void bucket_scan(const int* __restrict__ counts,
                                                   int* __restrict__ basep,
                                                   int* __restrict__ rowptr) {
    __shared__ int lds[512];
    const int tid = threadIdx.x;
    int v = (tid < NBUCK) ? counts[tid] : 0;
    lds[tid] = v;
    __syncthreads();
    for (int off = 1; off < 512; off <<= 1) {
        int t = (tid >= off) ? lds[tid - off] : 0;
        __syncthreads();
        lds[tid] += t;
        __syncthreads();
    }
    if (tid < NBUCK) basep[tid] = lds[tid] - v;
    if (tid == 0) rowptr[NN] = ETOT;
}

__global__ __launch_bounds__(256) void bucket_to_csr(const unsigned* __restrict__ buckets,
                                                     const int* __restrict__ bucket_counts,
                                                     const int* __restrict__ bucket_base,
                                                     int* __restrict__ rowptr,
                                                     int* __restrict__ csr) {
    __shared__ int h[128], c[128], sc[128];
    const int b = blockIdx.x, tid = threadIdx.x;
    const int nb   = bucket_counts[b];
    const int base = bucket_base[b];

    if (tid < 128) h[tid] = 0;
    __syncthreads();
    for (int i = tid; i < nb; i += 256) {
        unsigned p = buckets[(size_t)b * BCAP + i];
        atomicAdd(&h[p >> 16], 1);
    }
    __syncthreads();
    if (tid < 128) sc[tid] = h[tid];
    __syncthreads();
    for (int off = 1; off < 128; off <<= 1) {
        int t = (tid < 128 && tid >= off) ? sc[tid - off] : 0;
        __syncthreads();
        if (tid < 128) sc[tid] += t;
        __syncthreads();
    }
    if (tid < 128) {
        int excl = sc[tid] - h[tid];
        c[tid] = excl;
        int node = (b << 7) + tid;
        if (node < NN) rowptr[node] = base + excl;
    }
    __syncthreads();
    for (int i = tid; i < nb; i += 256) {
        unsigned p = buckets[(size_t)b * BCAP + i];
        int pos = atomicAdd(&c[p >> 16], 1);
        csr[base + pos] = (int)(p & 0xFFFFu);
    }
}

// ---------------- dtype conversions ----------------
__global__ void f32_to_f16_vec(const float* __restrict__ in, __half* __restrict__ out,
                               int n4) {
    int i = blockIdx.x * 256 + threadIdx.x;
    if (i >= n4) return;
    float4 v = *(const float4*)&in[(size_t)i * 4];
    __half h[4] = {__float2half(v.x), __float2half(v.y), __float2half(v.z), __float2half(v.w)};
    *(uint2*)&out[(size_t)i * 4] = *(uint2*)h;
}

__global__ void w_transpose_f16(const float* __restrict__ W, __half* __restrict__ Wt,
                                int K) {
    int idx = blockIdx.x * 256 + threadIdx.x;
    if (idx >= K * HC) return;
    int n = idx / K, k = idx - n * K;
    Wt[idx] = __float2half(W[(size_t)k * HC + n]);
}

// ---- f16 MFMA GEMM + fused attention-score epilogue ----
__global__ __launch_bounds__(256) void gemm_f16(const __half* __restrict__ A16,
                                                const __half* __restrict__ Bt16,
                                                __half* __restrict__ C16,
                                                const float* __restrict__ a_src,
                                                const float* __restrict__ a_dst,
                                                float* __restrict__ es,
                                                float* __restrict__ ed,
                                                int M, int K) {
    __shared__ char lds[32768];
    const int tid  = threadIdx.x;
    const int m0   = blockIdx.y * 128;
    const int n0   = blockIdx.x * 128;
    const int wid  = tid >> 6, lane = tid & 63;
    const int wr   = wid >> 1, wc = wid & 1;
    const int l15  = lane & 15, l4 = lane >> 4;
    const int trow = tid >> 3;
    const int tcol = (tid & 7) * 8;

    f32x4 acc[4][4] = {};

    for (int k0 = 0; k0 < K; k0 += 64) {
        __syncthreads();
#pragma unroll
        for (int it = 0; it < 4; ++it) {
            int row = trow + it * 32;
            uint4 v = make_uint4(0u, 0u, 0u, 0u);
            int gr = m0 + row;
            if (gr < M) v = *(const uint4*)&A16[(size_t)gr * K + k0 + tcol];
            int off = (row * 128 + tcol * 2) ^ ((row & 7) << 4);
            *(uint4*)(lds + off) = v;
            uint4 w = *(const uint4*)&Bt16[(size_t)(n0 + row) * K + k0 + tcol];
            int offb = 16384 + ((row * 128 + tcol * 2) ^ ((row & 7) << 4));
            *(uint4*)(lds + offb) = w;
        }
        __syncthreads();
#pragma unroll
        for (int ks = 0; ks < 2; ++ks) {
            f16x8 af[4], bf[4];
#pragma unroll
            for (int i = 0; i < 4; ++i) {
                int rowA = wr * 64 + i * 16 + l15;
                int offA = (rowA * 128 + ks * 64 + l4 * 16) ^ ((rowA & 7) << 4);
                af[i] = *(const f16x8*)(lds + offA);
                int rowB = wc * 64 + i * 16 + l15;
                int offB = 16384 + ((rowB * 128 + ks * 64 + l4 * 16) ^ ((rowB & 7) << 4));
                bf[i] = *(const f16x8*)(lds + offB);
            }
#pragma unroll
            for (int i = 0; i < 4; ++i)
#pragma unroll
                for (int j = 0; j < 4; ++j)
                    acc[i][j] = __builtin_amdgcn_mfma_f32_16x16x32_f16(af[i], bf[j], acc[i][j], 0, 0, 0);
        }
    }
#pragma unroll
    for (int i = 0; i < 4; ++i) {
#pragma unroll
        for (int r = 0; r < 4; ++r) {
            int row = m0 + wr * 64 + i * 16 + l4 * 4 + r;
            if (row < M) {
#pragma unroll
                for (int j = 0; j < 4; ++j) {
                    int col = n0 + wc * 64 + j * 16 + l15;
                    C16[(size_t)row * HC + col] = __float2half(acc[i][j][r]);
                }
            }
        }
    }
    const int hd = blockIdx.x * 2 + wc;
    float as_[4], ad_[4];
#pragma unroll
    for (int j = 0; j < 4; ++j) {
        int c = j * 16 + l15;
        as_[j] = a_src[hd * CH + c];
        ad_[j] = a_dst[hd * CH + c];
    }
#pragma unroll
    for (int i = 0; i < 4; ++i) {
#pragma unroll
        for (int r = 0; r < 4; ++r) {
            float ps = 0.f, pd = 0.f;
#pragma unroll
            for (int j = 0; j < 4; ++j) {
                ps = fmaf(acc[i][j][r], as_[j], ps);
                pd = fmaf(acc[i][j][r], ad_[j], pd);
            }
#pragma unroll
            for (int mm = 8; mm; mm >>= 1) {
                ps += __shfl_xor(ps, mm);
                pd += __shfl_xor(pd, mm);
            }
            int row = m0 + wr * 64 + i * 16 + l4 * 4 + r;
            if (l15 == 0 && row < M) {
                es[row * NH + hd] = ps;
                ed[row * NH + hd] = pd;
            }
        }
    }
}

// ------- fused softmax + gather: wave per node -------
// pass1: online (m,s) per head over edges; pass2: paired-edge feature gather,
// alpha recomputed inline in f32. Lanes 0-31 = even edge, 32-63 = odd edge;
// each lane owns 8 channels (16B loads). Cross-half shfl merge, lanes<32 store.
__global__ __launch_bounds__(256) void gat_fused(const __half* __restrict__ hfeat,
                                                 const float* __restrict__ es,
                                                 const float* __restrict__ ed,
                                                 const int* __restrict__ rowptr,
                                                 const int* __restrict__ csr_src,
                                                 const float* __restrict__ bias,
                                                 __half* __restrict__ out16) {
    const int node = blockIdx.x * 4 + (threadIdx.x >> 6);
    const int lane = threadIdx.x & 63;
    if (node >= NN) return;
    const int start = rowptr[node];
    const int deg   = rowptr[node + 1] - start;

    float4 ed4 = *(const float4*)&ed[node * NH];
    float edn[NH] = {ed4.x, ed4.y, ed4.z, ed4.w};

    // ---- pass 1: per-head online softmax stats ----
    float m[NH], s[NH];
#pragma unroll
    for (int h = 0; h < NH; ++h) { m[h] = -1e30f; s[h] = 0.f; }
    for (int j = lane; j < deg; j += 64) {
        int src = csr_src[start + j];
        float4 e4 = *(const float4*)&es[src * NH];
        float ev[NH] = {e4.x, e4.y, e4.z, e4.w};
#pragma unroll
        for (int h = 0; h < NH; ++h) {
            float e = ev[h] + edn[h];
            e = (e > 0.f) ? e : NEG_SLOPE * e;
            sm_combine(m[h], s[h], e, 1.0f);
        }
    }
#pragma unroll
    for (int h = 0; h < NH; ++h)
#pragma unroll
        for (int off = 32; off > 0; off >>= 1) {
            float om = __shfl_xor(m[h], off);
            float os = __shfl_xor(s[h], off);
            sm_combine(m[h], s[h], om, os);
        }

    // ---- pass 2: paired-edge gather ----
    const int sub = lane >> 5;        // 0: even edge, 1: odd edge
    const int cl  = lane & 31;        // channel-lane, owns ch [cl*8, cl*8+8)
    const int hsel = cl >> 3;         // head = (cl*8)/64
    const float mh  = m[hsel];
    const float ish = 1.0f / s[hsel];
    const float ehn = edn[hsel];

    float acc[8] = {0.f, 0.f, 0.f, 0.f, 0.f, 0.f, 0.f, 0.f};
    int j = 0;
    for (; j + 3 < deg; j += 4) {
        int jj0 = start + j + sub;
        int jj1 = start + j + 2 + sub;
        int s0 = csr_src[jj0];
        int s1 = csr_src[jj1];
        float e0 = es[s0 * NH + hsel] + ehn;
        float e1 = es[s1 * NH + hsel] + ehn;
        e0 = (e0 > 0.f) ? e0 : NEG_SLOPE * e0;
        e1 = (e1 > 0.f) ? e1 : NEG_SLOPE * e1;
        float a0 = __expf(e0 - mh) * ish;
        float a1 = __expf(e1 - mh) * ish;
        uint4 r0 = *(const uint4*)&hfeat[(size_t)s0 * HC + cl * 8];
        uint4 r1 = *(const uint4*)&hfeat[(size_t)s1 * HC + cl * 8];
        const unsigned* w0 = &r0.x;
        const unsigned* w1 = &r1.x;
#pragma unroll
        for (int q = 0; q < 4; ++q) {
            float2 f0 = __half22float2(*reinterpret_cast<const __half2*>(&w0[q]));
            float2 f1 = __half22float2(*reinterpret_cast<const __half2*>(&w1[q]));
            acc[q * 2]     = fmaf(a0, f0.x, acc[q * 2]);
            acc[q * 2 + 1] = fmaf(a0, f0.y, acc[q * 2 + 1]);
            acc[q * 2]     = fmaf(a1, f1.x, acc[q * 2]);
            acc[q * 2 + 1] = fmaf(a1, f1.y, acc[q * 2 + 1]);
        }
    }
    for (; j < deg; j += 2) {
        int jj = j + sub;
        if (jj < deg) {
            int s0 = csr_src[start + jj];
            float e0 = es[s0 * NH + hsel] + ehn;
            e0 = (e0 > 0.f) ? e0 : NEG_SLOPE * e0;
            float a0 = __expf(e0 - mh) * ish;
            uint4 r0 = *(const uint4*)&hfeat[(size_t)s0 * HC + cl * 8];
            const unsigned* w0 = &r0.x;
#pragma unroll
            for (int q = 0; q < 4; ++q) {
                float2 f0 = __half22float2(*reinterpret_cast<const __half2*>(&w0[q]));
                acc[q * 2]     = fmaf(a0, f0.x, acc[q * 2]);
                acc[q * 2 + 1] = fmaf(a0, f0.y, acc[q * 2 + 1]);
            }
        }
    }
    // merge odd-edge half into even-edge half
#pragma unroll
    for (int q = 0; q < 8; ++q) acc[q] += __shfl_xor(acc[q], 32);

    if (lane < 32) {
        float4 b0 = *(const float4*)&bias[cl * 8];
        float4 b1 = *(const float4*)&bias[cl * 8 + 4];
        const float* bp0 = &b0.x;
        const float* bp1 = &b1.x;
        __half h[8];
#pragma unroll
        for (int q = 0; q < 4; ++q) h[q]     = __float2half(fmaxf(acc[q]     + bp0[q], 0.f));
#pragma unroll
        for (int q = 0; q < 4; ++q) h[4 + q] = __float2half(fmaxf(acc[4 + q] + bp1[q], 0.f));
        *(uint4*)&out16[(size_t)node * HC + cl * 8] = *(uint4*)h;
    }
}

// ---------------- mean pool + final linear ----------------
__global__ __launch_bounds__(256) void pool_sum(const __half* __restrict__ h,
                                                const int* __restrict__ batch,
                                                float* __restrict__ sums) {
    int t  = threadIdx.x;
    int n0 = blockIdx.x * 128;
    if (n0 >= NN) return;
    int cur = batch[n0];
    float acc = 0.f;
    int nend = min(n0 + 128, NN);
    for (int n = n0; n < nend; ++n) {
        int g = batch[n];
        if (g != cur) {
            atomicAdd(&sums[cur * HC + t], acc);
            acc = 0.f; cur = g;
        }
        acc += __half2float(h[(size_t)n * HC + t]);
    }
    atomicAdd(&sums[cur * HC + t], acc);
}

__global__ void batch_bounds(const int* __restrict__ batch,
                             int* __restrict__ beg, int* __restrict__ end) {
    int i = blockIdx.x * 256 + threadIdx.x;
    if (i >= NN) return;
    int g = batch[i];
    if (i == 0      || batch[i - 1] != g) beg[g] = i;
    if (i == NN - 1 || batch[i + 1] != g) end[g] = i + 1;
}

__global__ __launch_bounds__(256) void final_linear(const float* __restrict__ sums,
                                                    const int* __restrict__ beg,
                                                    const int* __restrict__ end,
                                                    const float* __restrict__ Wlin,
                                                    const float* __restrict__ blin,
                                                    float* __restrict__ out) {
    int idx = blockIdx.x * 256 + threadIdx.x;
    if (idx >= NG * NOUT) return;
    int g = idx >> 4, o = idx & 15;
    float cnt = (float)(end[g] - beg[g]);
    float invc = 1.f / fmaxf(cnt, 1.f);
    float acc = 0.f;
    for (int k = 0; k < HC; ++k) acc += sums[g * HC + k] * Wlin[k * NOUT + o];
    out[idx] = acc * invc + blin[o];
}

// ---------------- launch ----------------
extern "C" void kernel_launch(void* const* d_in, const int* in_sizes, int n_in,
                              void* d_out, int out_size, void* d_ws, size_t ws_size,
                              hipStream_t stream) {
    const float* x      = (const float*)d_in[0];
    const int*   ei     = (const int*)d_in[1];
    const int*   batch  = (const int*)d_in[2];
    const float* W1     = (const float*)d_in[3];
    const float* a_src1 = (const float*)d_in[4];
    const float* a_dst1 = (const float*)d_in[5];
    const float* b1     = (const float*)d_in[6];
    const float* W2     = (const float*)d_in[7];
    const float* a_src2 = (const float*)d_in[8];
    const float* a_dst2 = (const float*)d_in[9];
    const float* b2     = (const float*)d_in[10];
    const float* Wlin   = (const float*)d_in[11];
    const float* blin   = (const float*)d_in[12];
    float* out = (float*)d_out;

    char* p = (char*)d_ws;
    auto take = [&](size_t bytes) {
        char* r = p;
        p += (bytes + 255) & ~(size_t)255;
        return r;
    };
    __half*   bufT16 = (__half*)take((size_t)NN * HC * 2);
    __half*   bufH16 = (__half*)take((size_t)NN * HC * 2);
    __half*   x16    = (__half*)take((size_t)NN * FIN * 2);
    __half*   w1t    = (__half*)take((size_t)FIN * HC * 2);
    __half*   w2t    = (__half*)take((size_t)HC * HC * 2);
    float*    es     = (float*)take((size_t)NN * NH * 4);
    float*    ed     = (float*)take((size_t)NN * NH * 4);
    int*      rowptr = (int*)take((size_t)(NN + 1) * 4);
    int*      csr    = (int*)take((size_t)ETOT * 4);
    unsigned* buckets= (unsigned*)take((size_t)NBUCK * BCAP * 4);
    int*      bcnt   = (int*)take((size_t)NBUCK * 4);
    int*      bbase  = (int*)take((size_t)NBUCK * 4);
    float*    sums   = (float*)take((size_t)NG * HC * 4);
    int*      gbeg   = (int*)take((size_t)NG * 4);
    int*      gend   = (int*)take((size_t)NG * 4);

    hipMemsetAsync(bcnt, 0, (size_t)NBUCK * 4, stream);
    hipMemsetAsync(sums, 0, (size_t)NG * HC * 4, stream);
    hipMemsetAsync(gbeg, 0, (size_t)NG * 4, stream);
    hipMemsetAsync(gend, 0, (size_t)NG * 4, stream);

    // CSR build (bucketed) + conversions
    edge_bucket<<<NEB, 256, 0, stream>>>(ei, bcnt, buckets);
    bucket_scan<<<1, 512, 0, stream>>>(bcnt, bbase, rowptr);
    bucket_to_csr<<<NBUCK, 256, 0, stream>>>(buckets, bcnt, bbase, rowptr, csr);
    f32_to_f16_vec<<<(NN * FIN / 4 + 255) / 256, 256, 0, stream>>>(x, x16, NN * FIN / 4);
    w_transpose_f16<<<(FIN * HC + 255) / 256, 256, 0, stream>>>(W1, w1t, FIN);
    w_transpose_f16<<<(HC * HC + 255) / 256, 256, 0, stream>>>(W2, w2t, HC);

    // layer 1
    gemm_f16<<<dim3(2, (NN + 127) / 128), 256, 0, stream>>>(x16, w1t, bufT16,
                                                            a_src1, a_dst1, es, ed, NN, FIN);
    gat_fused<<<(NN + 3) / 4, 256, 0, stream>>>(bufT16, es, ed, rowptr, csr, b1, bufH16);

    // layer 2
    gemm_f16<<<dim3(2, (NN + 127) / 128), 256, 0, stream>>>(bufH16, w2t, bufT16,
                                                            a_src2, a_dst2, es, ed, NN, HC);
    gat_fused<<<(NN + 3) / 4, 256, 0, stream>>>(bufT16, es, ed, rowptr, csr, b2, bufH16);

    // pool + head
    pool_sum<<<(NN + 127) / 128, 256, 0, stream>>>(bufH16, batch, sums);
    batch_bounds<<<(NN + 255) / 256, 256, 0, stream>>>(batch, gbeg, gend);
    final_linear<<<4, 256, 0, stream>>>(sums, gbeg, gend, Wlin, blin, out);
}